// Round 3
// baseline (290358.643 us; speedup 1.0000x reference)
//
#include <hip/hip_runtime.h>

typedef unsigned short u16;
typedef __bf16 bf16x8 __attribute__((ext_vector_type(8)));
typedef float f32x4 __attribute__((ext_vector_type(4)));

#define EPSC 1e-6f

// ---------- helpers ----------
__device__ __forceinline__ float b2f(u16 x) { return __uint_as_float(((unsigned)x) << 16); }
__device__ __forceinline__ u16 f2b(float f) {
    unsigned u = __float_as_uint(f);
    unsigned r = (u + 0x7fffu + ((u >> 16) & 1u)) >> 16;
    return (u16)r;
}
__device__ __forceinline__ float softplusf(float x) {
    return fmaxf(x, 0.f) + log1pf(__expf(-fabsf(x)));
}

// ---------- conversion / transpose kernels ----------
__global__ void conv_x4(u16* __restrict__ dst, const float* __restrict__ x) {
    size_t i4 = (size_t)blockIdx.x * 256 + threadIdx.x;
    size_t o = i4 * 4;
    int d = (int)(o & 511);
    int b = (int)((o >> 9) & 255);
    int t = (int)(o >> 17);
    float4 v = *(const float4*)(x + ((size_t)b * 256 + t) * 512 + d);
    unsigned p0 = (unsigned)f2b(v.x) | ((unsigned)f2b(v.y) << 16);
    unsigned p1 = (unsigned)f2b(v.z) | ((unsigned)f2b(v.w) << 16);
    *(uint2*)(dst + o) = make_uint2(p0, p1);
}

__global__ void conv_f32_bf16(u16* __restrict__ dst, const float* __restrict__ src, int n) {
    int i = blockIdx.x * 256 + threadIdx.x;
    if (i < n) dst[i] = f2b(src[i]);
}

__global__ void tr_conv(u16* __restrict__ dst, const float* __restrict__ src,
                        int R, int C, int ld) {
    int idx = blockIdx.x * 256 + threadIdx.x;
    if (idx >= R * C) return;
    int c = idx / R, r = idx % R;
    dst[idx] = f2b(src[(size_t)r * ld + c]);
}

__global__ void init_ctr(unsigned* bar) {
    if (threadIdx.x < 512) bar[threadIdx.x] = 0u;
}

// ---------- generic 128x128 bf16 MFMA GEMM (phase A/C) ----------
enum { EPI_PARTIAL = 0, EPI_BF16_RELU = 1, EPI_BF16_NONE = 2,
       EPI_F32_RELU = 3, EPI_F32_SP = 4, EPI_F32_SIG = 5 };

template <int EPI>
__global__ __launch_bounds__(256)
void gemm128(const u16* __restrict__ A0, const u16* __restrict__ A1,
             int lda0, int lda1, int kSplit,
             const u16* __restrict__ Wt, int ldw,
             const float* __restrict__ bias,
             u16* __restrict__ Cb, float* __restrict__ Cf,
             int M, int N, int K, int kChunk) {
    __shared__ __align__(16) u16 As[128 * 72];
    __shared__ __align__(16) u16 Bs[128 * 72];
    const int tid = threadIdx.x;
    const int wid = tid >> 6, lane = tid & 63;
    const int wm = wid >> 1, wn = wid & 1;
    const int lr = lane & 15, lk = lane >> 4;
    const int m0 = blockIdx.y * 128, n0 = blockIdx.x * 128;
    const int kBeg = blockIdx.z * kChunk;
    const int rsub = lane >> 3;
    const int csub = (lane & 7) * 8;

    f32x4 acc[4][4];
#pragma unroll
    for (int i = 0; i < 4; i++)
#pragma unroll
        for (int j = 0; j < 4; j++) { f32x4 z = {0.f, 0.f, 0.f, 0.f}; acc[i][j] = z; }

    for (int kt = 0; kt < kChunk; kt += 64) {
        const int k0 = kBeg + kt;
        const u16* Ap; int kk, lda;
        if (k0 < kSplit) { Ap = A0; kk = k0; lda = lda0; }
        else             { Ap = A1; kk = k0 - kSplit; lda = lda1; }
        uint4 ra[4], rb[4];
#pragma unroll
        for (int i = 0; i < 4; i++) {
            const int q = wid * 4 + i;
            const int r = q * 8 + rsub;
            ra[i] = *(const uint4*)(Ap + (size_t)(m0 + r) * lda + kk + csub);
            rb[i] = *(const uint4*)(Wt + (size_t)(n0 + r) * ldw + k0 + csub);
        }
        __syncthreads();
#pragma unroll
        for (int i = 0; i < 4; i++) {
            const int q = wid * 4 + i;
            const int r = q * 8 + rsub;
            *(uint4*)&As[r * 72 + csub] = ra[i];
            *(uint4*)&Bs[r * 72 + csub] = rb[i];
        }
        __syncthreads();
#pragma unroll
        for (int s = 0; s < 2; s++) {
            bf16x8 af[4], bfr[4];
#pragma unroll
            for (int i = 0; i < 4; i++)
                af[i] = *(const bf16x8*)&As[(wm * 64 + i * 16 + lr) * 72 + s * 32 + lk * 8];
#pragma unroll
            for (int j = 0; j < 4; j++)
                bfr[j] = *(const bf16x8*)&Bs[(wn * 64 + j * 16 + lr) * 72 + s * 32 + lk * 8];
#pragma unroll
            for (int i = 0; i < 4; i++)
#pragma unroll
                for (int j = 0; j < 4; j++)
                    acc[i][j] = __builtin_amdgcn_mfma_f32_16x16x32_bf16(af[i], bfr[j], acc[i][j], 0, 0, 0);
        }
    }

    const int rowb = m0 + wm * 64, colb = n0 + wn * 64;
#pragma unroll
    for (int i = 0; i < 4; i++) {
#pragma unroll
        for (int j = 0; j < 4; j++) {
            const int col = colb + j * 16 + lr;
#pragma unroll
            for (int r = 0; r < 4; r++) {
                const int row = rowb + i * 16 + lk * 4 + r;
                float v = acc[i][j][r];
                if (EPI == EPI_PARTIAL) {
                    Cf[(size_t)blockIdx.z * ((size_t)M * N) + (size_t)row * N + col] = v;
                } else {
                    if (bias) v += bias[col];
                    if (EPI == EPI_BF16_RELU || EPI == EPI_F32_RELU) v = fmaxf(v, 0.f);
                    else if (EPI == EPI_F32_SP)  v = softplusf(v);
                    else if (EPI == EPI_F32_SIG) v = 1.f / (1.f + __expf(-v));
                    if (EPI == EPI_BF16_RELU || EPI == EPI_BF16_NONE) Cb[(size_t)row * N + col] = f2b(v);
                    else Cf[(size_t)row * N + col] = v;
                }
            }
        }
    }
}

// ---------- workspace layout (bytes) ----------
static constexpr size_t oPHIXWT  = 0;                      // [1024][512]
static constexpr size_t oWCATT   = 1048576;                // [2048][2048]
static constexpr size_t oEMW2T   = 9437184;                // [128][1024]
static constexpr size_t oESW2T   = 9699328;
static constexpr size_t oWIHPHIT = 9961472;                // [3072][1024]
static constexpr size_t oWIHZT   = 16252928;               // [3072][128]
static constexpr size_t oPMW1T   = 17039360;
static constexpr size_t oPMW2T   = 19136512;
static constexpr size_t oPSW1T   = 19398656;
static constexpr size_t oPSW2T   = 21495808;
static constexpr size_t oDMW1T   = 21757952;               // [1024][1152]
static constexpr size_t oDMW2T   = 24117248;               // [512][1024]
static constexpr size_t oHS      = 25165824;               // [T+1][B][H] bf16
static constexpr size_t oZBF     = 159907840;              // [T][B][Z] bf16
static constexpr size_t oT12     = 176685056;              // [256][2048] bf16
static constexpr size_t oBAR     = 177733632;              // 512 uints
static constexpr size_t oKLDT    = 177737728;
static constexpr size_t oNLLT    = 177738752;
static constexpr size_t oPHI     = 177739776;              // [65536][1024] bf16 (U1 in phase C)
static constexpr size_t oGIP     = 311957504;              // [65536][3072] bf16 (XbfT / PM / PS overlay)
static constexpr size_t WS_NEED  = 714610688;

static constexpr size_t NZ = (size_t)256 * 256 * 128;
static constexpr size_t O_Z  = 3;
static constexpr size_t O_MU = 3 + NZ;
static constexpr size_t O_STD = 3 + 2 * NZ;
static constexpr size_t O_XM = 3 + 3 * NZ;

// ---------- hierarchical grid barrier ----------
__device__ __forceinline__ void gbar(unsigned* bar, unsigned* nbar) {
    __syncthreads();
    if (threadIdx.x == 0) {
        const unsigned n = (*nbar)++;
        __threadfence();
        unsigned* sub = bar + (blockIdx.x & 7) * 32;
        const unsigned old = __hip_atomic_fetch_add(sub, 1u, __ATOMIC_ACQ_REL, __HIP_MEMORY_SCOPE_AGENT);
        if (old == n * 32u + 31u)
            __hip_atomic_fetch_add(bar + 256, 1u, __ATOMIC_ACQ_REL, __HIP_MEMORY_SCOPE_AGENT);
        while (__hip_atomic_load(bar + 256, __ATOMIC_ACQUIRE, __HIP_MEMORY_SCOPE_AGENT) < (n + 1u) * 8u)
            __builtin_amdgcn_s_sleep(2);
        __threadfence();
    }
    __syncthreads();
}

// ---------- persistent sequential-phase kernel ----------
__global__ __launch_bounds__(256)
void vrnn_seq(const float* __restrict__ eps,
              const float* __restrict__ em_b1, const float* __restrict__ es_b1,
              const float* __restrict__ em_b2, const float* __restrict__ es_b2,
              const float* __restrict__ gbih, const float* __restrict__ gbhh,
              char* ws, float* out) {
    __shared__ __align__(16) u16 SA[128 * 72];
    __shared__ __align__(16) u16 SB[128 * 72];
    __shared__ __align__(16) float epsL[2048];
    __shared__ float zmL[2048], zsL[2048];
    __shared__ __align__(16) u16 zbfL[2048];

    const int bx = blockIdx.x, tid = threadIdx.x;
    const int wid = tid >> 6, lane = tid & 63;
    const int lr = lane & 15, lk = lane >> 4;
    const int wm = wid >> 1, wn = wid & 1;
    const int sr = tid >> 3, sc = (tid & 7) * 8;

    const u16* wcatT = (const u16*)(ws + oWCATT);
    const u16* emW2T = (const u16*)(ws + oEMW2T);
    const u16* esW2T = (const u16*)(ws + oESW2T);
    const u16* wihZT = (const u16*)(ws + oWIHZT);
    const u16* PHI   = (const u16*)(ws + oPHI);
    const u16* GIP   = (const u16*)(ws + oGIP);
    u16* HS   = (u16*)(ws + oHS);
    u16* ZBFg = (u16*)(ws + oZBF);
    u16* T12g = (u16*)(ws + oT12);
    unsigned* bar = (unsigned*)(ws + oBAR);

    float* outZ  = out + O_Z;
    float* outMu = out + O_MU;
    float* outSd = out + O_STD;

    unsigned nbar = 0;

#define W1_LOAD(RA, RB, KT) {                                                        \
    const int k0_ = (KT) * 64;                                                       \
    const u16* Ap_ = (k0_ < 1024) ? A0t : A1t;                                       \
    const int kk_ = (k0_ < 1024) ? k0_ : k0_ - 1024;                                 \
    _Pragma("unroll")                                                                \
    for (int i_ = 0; i_ < 4; i_++)                                                   \
        RA[i_] = *(const uint4*)(Ap_ + (size_t)(mI*128 + i_*32 + sr) * 1024 + kk_ + sc); \
    _Pragma("unroll")                                                                \
    for (int i_ = 0; i_ < 4; i_++)                                                   \
        RB[i_] = *(const uint4*)(Bb + (size_t)(i_*32 + sr) * 2048 + k0_ + sc);       \
}

#define W1_STAGE(RA, RB) {                                                           \
    __syncthreads();                                                                 \
    _Pragma("unroll")                                                                \
    for (int i_ = 0; i_ < 4; i_++) *(uint4*)&SA[(i_*32 + sr) * 72 + sc] = RA[i_];    \
    _Pragma("unroll")                                                                \
    for (int i_ = 0; i_ < 4; i_++) *(uint4*)&SB[(i_*32 + sr) * 72 + sc] = RB[i_];    \
    __syncthreads();                                                                 \
}

#define W1_MFMA() {                                                                  \
    _Pragma("unroll")                                                                \
    for (int s_ = 0; s_ < 2; s_++) {                                                 \
        bf16x8 af_[4], bf_[4];                                                       \
        _Pragma("unroll")                                                            \
        for (int i_ = 0; i_ < 4; i_++)                                               \
            af_[i_] = *(const bf16x8*)&SA[(wm*64 + i_*16 + lr) * 72 + s_*32 + lk*8]; \
        _Pragma("unroll")                                                            \
        for (int j_ = 0; j_ < 4; j_++)                                               \
            bf_[j_] = *(const bf16x8*)&SB[(wn*64 + j_*16 + lr) * 72 + s_*32 + lk*8]; \
        _Pragma("unroll")                                                            \
        for (int i_ = 0; i_ < 4; i_++)                                               \
            _Pragma("unroll")                                                        \
            for (int j_ = 0; j_ < 4; j_++)                                           \
                acc[i_][j_] = __builtin_amdgcn_mfma_f32_16x16x32_bf16(af_[i_], bf_[j_], acc[i_][j_], 0, 0, 0); \
    }                                                                                \
}

#pragma unroll 1
    for (int t = 0; t < 256; t++) {
        // ======== window 1: T12 = [h_t | phi_t] @ wcat  (blocks 0..31, 128x128 tiles) ========
        if (bx < 32) {
            const int mI = bx & 1, nI = bx >> 1;
            const u16* Bb  = wcatT + (size_t)(nI * 128) * 2048;
            const u16* A0t = HS  + (size_t)t * 262144;
            const u16* A1t = PHI + (size_t)t * 262144;
            f32x4 acc[4][4];
#pragma unroll
            for (int i = 0; i < 4; i++)
#pragma unroll
                for (int j = 0; j < 4; j++) { f32x4 z = {0.f,0.f,0.f,0.f}; acc[i][j] = z; }
            uint4 ra0[4], rb0[4], ra1[4], rb1[4];
            W1_LOAD(ra0, rb0, 0);
            W1_LOAD(ra1, rb1, 1);
#pragma unroll 1
            for (int kt = 0; kt < 32; kt += 2) {
                W1_STAGE(ra0, rb0);
                if (kt + 2 < 32) W1_LOAD(ra0, rb0, kt + 2);
                W1_MFMA();
                W1_STAGE(ra1, rb1);
                if (kt + 3 < 32) W1_LOAD(ra1, rb1, kt + 3);
                W1_MFMA();
            }
#pragma unroll
            for (int a = 0; a < 4; a++)
#pragma unroll
                for (int b = 0; b < 4; b++) {
                    const int col = nI*128 + wn*64 + b*16 + lr;
                    const float bb = (col < 1024) ? em_b1[col] : es_b1[col - 1024];
#pragma unroll
                    for (int r = 0; r < 4; r++) {
                        const int row = mI*128 + wm*64 + a*16 + lk*4 + r;
                        T12g[(size_t)row * 2048 + col] = f2b(fmaxf(acc[a][b][r] + bb, 0.f));
                    }
                }
        }
        gbar(bar, &nbar);

        // ======== window 2: zm/zs -> z -> GRU -> h_{t+1}  (blocks 0..15, 16 rows each) ========
        if (bx < 16) {
            const int r0 = bx * 16;
            // stage eps rows into LDS
            const float* epsg = eps + (size_t)t * 32768 + (size_t)r0 * 128;
#pragma unroll
            for (int q = 0; q < 2; q++)
                *(float4*)&epsL[tid * 8 + q * 4] = *(const float4*)(epsg + tid * 8 + q * 4);

            // ---- zm/zs: wave = (half, colgroup); 4 col-tiles per wave, K=1024 in 2 chunks ----
            const int half = wid >> 1, jg = wid & 1;
            const u16* W2w = half ? esW2T : emW2T;
            const u16* Arow = T12g + (size_t)(r0 + lr) * 2048 + half * 1024;
            f32x4 accz[4];
#pragma unroll
            for (int j = 0; j < 4; j++) { f32x4 z = {0.f,0.f,0.f,0.f}; accz[j] = z; }
#pragma unroll
            for (int kc = 0; kc < 2; kc++) {
                bf16x8 af[16];
#pragma unroll
                for (int ks = 0; ks < 16; ks++)
                    af[ks] = *(const bf16x8*)(Arow + kc*512 + ks*32 + lk*8);
#pragma unroll
                for (int j4 = 0; j4 < 4; j4++) {
                    const int j = jg*4 + j4;
                    const u16* Wr = W2w + (size_t)(j*16 + lr) * 1024 + kc*512 + lk*8;
#pragma unroll
                    for (int ks = 0; ks < 16; ks++) {
                        bf16x8 bf = *(const bf16x8*)(Wr + ks*32);
                        accz[j4] = __builtin_amdgcn_mfma_f32_16x16x32_bf16(af[ks], bf, accz[j4], 0, 0, 0);
                    }
                }
            }
            float* dstL = half ? zsL : zmL;
#pragma unroll
            for (int j4 = 0; j4 < 4; j4++) {
                const int colg = (jg*4 + j4)*16 + lr;
#pragma unroll
                for (int r = 0; r < 4; r++) {
                    const int m = lk*4 + r;
                    float v = accz[j4][r];
                    if (!half) dstL[m*128 + colg] = fmaxf(v + em_b2[colg], 0.f);
                    else       dstL[m*128 + colg] = softplusf(v + es_b2[colg]);
                }
            }
            __syncthreads();

            // ---- z = zm + zs*eps; write outputs ----
#pragma unroll
            for (int q = 0; q < 8; q++) {
                const int e = q*256 + tid;
                const float zm = zmL[e], zs = zsL[e];
                const float z = zm + zs * epsL[e];
                const size_t o = (size_t)t*32768 + (size_t)r0*128 + e;
                outMu[o] = zm; outSd[o] = zs; outZ[o] = z;
                const u16 zb = f2b(z);
                ZBFg[o] = zb; zbfL[e] = zb;
            }
            __syncthreads();

            // ---- GRU: h_{t+1} rows r0..r0+15; wave handles 16 col-tiles of 16 ----
            bf16x8 zf[4];
#pragma unroll
            for (int ks = 0; ks < 4; ks++)
                zf[ks] = *(const bf16x8*)&zbfL[lr*128 + ks*32 + lk*8];
            const u16* gipt = GIP + (size_t)t * 786432;   // [256][3072]
            u16* HSn = HS + (size_t)(t+1) * 262144;
#pragma unroll 1
            for (int i = 0; i < 16; i++) {
                const int ct = wid*16 + i;
                const int col = ct*16 + lr;
                f32x4 aR = {0.f,0.f,0.f,0.f}, aU = {0.f,0.f,0.f,0.f}, aN = {0.f,0.f,0.f,0.f};
#pragma unroll
                for (int ks = 0; ks < 4; ks++) {
                    const int ko = ks*32 + lk*8;
                    bf16x8 bR = *(const bf16x8*)(wihZT + (size_t)(       ct*16 + lr)*128 + ko);
                    bf16x8 bU = *(const bf16x8*)(wihZT + (size_t)(1024 + ct*16 + lr)*128 + ko);
                    bf16x8 bN = *(const bf16x8*)(wihZT + (size_t)(2048 + ct*16 + lr)*128 + ko);
                    aR = __builtin_amdgcn_mfma_f32_16x16x32_bf16(zf[ks], bR, aR, 0, 0, 0);
                    aU = __builtin_amdgcn_mfma_f32_16x16x32_bf16(zf[ks], bU, aU, 0, 0, 0);
                    aN = __builtin_amdgcn_mfma_f32_16x16x32_bf16(zf[ks], bN, aN, 0, 0, 0);
                }
                const float bihR = gbih[col],        bhR = gbhh[col];
                const float bihU = gbih[1024 + col], bhU = gbhh[1024 + col];
                const float bihN = gbih[2048 + col], bhN = gbhh[2048 + col];
#pragma unroll
                for (int r = 0; r < 4; r++) {
                    const int b = r0 + lk*4 + r;
                    const u16* gp = gipt + (size_t)b * 3072;
                    const float gr = aR[r] + b2f(gp[col])        + bihR + bhR;
                    const float gu = aU[r] + b2f(gp[1024 + col]) + bihU + bhU;
                    float gn       = aN[r] + b2f(gp[2048 + col]) + bihN;
                    const float rr_ = 1.f / (1.f + __expf(-gr));
                    const float uu  = 1.f / (1.f + __expf(-gu));
                    gn += rr_ * bhN;
                    const float e2 = __expf(-2.f * fabsf(gn));
                    float th = (1.f - e2) / (1.f + e2);
                    th = (gn < 0.f) ? -th : th;
                    HSn[(size_t)b * 1024 + col] = f2b((1.f - uu) * th);
                }
            }
        }
        gbar(bar, &nbar);
    }
#undef W1_LOAD
#undef W1_STAGE
#undef W1_MFMA
}

// ---------- loss ----------
__global__ __launch_bounds__(256)
void loss_per_t(const float* __restrict__ x,
                const float* __restrict__ xm,
                const float* __restrict__ zm, const float* __restrict__ zs,
                const float* __restrict__ pm, const float* __restrict__ ps,
                float* __restrict__ kldT, float* __restrict__ nllT) {
    const int t = blockIdx.x, bb = threadIdx.x;
    float kld = 0.f, nll = 0.f;
    const size_t ozb = ((size_t)t * 256 + bb) * 128;
    for (int zz = 0; zz < 128; zz++) {
        const float qs = zs[ozb + zz], qm = zm[ozb + zz];
        const float pmv = pm[ozb + zz], psv = ps[ozb + zz];
        const float d = qm - pmv;
        kld += logf(psv + EPSC) - logf(qs + EPSC)
             + (qs * qs + d * d) / (2.f * psv * psv + EPSC) - 0.5f;
    }
    const size_t oxb = ((size_t)t * 256 + bb) * 512;
    const size_t oxi = ((size_t)bb * 256 + t) * 512;
    for (int dd = 0; dd < 512; dd++) {
        const float xv = x[oxi + dd];
        float m = xm[oxb + dd];
        m = fminf(fmaxf(m, 1e-6f), 1.f - 1e-6f);
        nll -= xv * logf(m) + (1.f - xv) * log1pf(-m);
    }
    __shared__ float sk[256], sn[256];
    sk[bb] = kld; sn[bb] = nll;
    __syncthreads();
    for (int s = 128; s > 0; s >>= 1) {
        if (bb < s) { sk[bb] += sk[bb + s]; sn[bb] += sn[bb + s]; }
        __syncthreads();
    }
    if (bb == 0) { kldT[t] = sk[0] / 256.f; nllT[t] = sn[0] / 256.f; }
}

__global__ __launch_bounds__(256)
void loss_final(const float* __restrict__ kldT, const float* __restrict__ nllT,
                float* __restrict__ out) {
    const int tid = threadIdx.x;
    __shared__ float s[256];
    s[tid] = kldT[tid] + nllT[tid];
    __syncthreads();
    for (int st = 128; st > 0; st >>= 1) {
        if (tid < st) s[tid] += s[tid + st];
        __syncthreads();
    }
    if (tid == 0) { out[0] = s[0]; out[1] = kldT[255]; out[2] = nllT[255]; }
}

extern "C" void kernel_launch(void* const* d_in, const int* in_sizes, int n_in,
                              void* d_out, int out_size, void* d_ws, size_t ws_size,
                              hipStream_t stream) {
    const float* x      = (const float*)d_in[0];
    const float* eps    = (const float*)d_in[1];
    const float* h0     = (const float*)d_in[2];
    const float* phix_w = (const float*)d_in[3];
    const float* phix_b = (const float*)d_in[4];
    const float* pm_w1  = (const float*)d_in[5];
    const float* pm_b1  = (const float*)d_in[6];
    const float* pm_w2  = (const float*)d_in[7];
    const float* pm_b2  = (const float*)d_in[8];
    const float* ps_w1  = (const float*)d_in[9];
    const float* ps_b1  = (const float*)d_in[10];
    const float* ps_w2  = (const float*)d_in[11];
    const float* ps_b2  = (const float*)d_in[12];
    const float* em_w1  = (const float*)d_in[13];
    const float* em_b1  = (const float*)d_in[14];
    const float* em_w2  = (const float*)d_in[15];
    const float* em_b2  = (const float*)d_in[16];
    const float* es_w1  = (const float*)d_in[17];
    const float* es_b1  = (const float*)d_in[18];
    const float* es_w2  = (const float*)d_in[19];
    const float* es_b2  = (const float*)d_in[20];
    const float* dm_w1  = (const float*)d_in[21];
    const float* dm_b1  = (const float*)d_in[22];
    const float* dm_w2  = (const float*)d_in[23];
    const float* dm_b2  = (const float*)d_in[24];
    const float* gwih   = (const float*)d_in[25];
    const float* gbih   = (const float*)d_in[26];
    const float* gbhh   = (const float*)d_in[27];
    float* out = (float*)d_out;

    if (ws_size < WS_NEED) return;
    char* w = (char*)d_ws;
    u16* phixWt  = (u16*)(w + oPHIXWT);
    u16* wcatT   = (u16*)(w + oWCATT);
    u16* emW2T   = (u16*)(w + oEMW2T);
    u16* esW2T   = (u16*)(w + oESW2T);
    u16* wihPhiT = (u16*)(w + oWIHPHIT);
    u16* wihZT   = (u16*)(w + oWIHZT);
    u16* pmW1T   = (u16*)(w + oPMW1T);
    u16* pmW2T   = (u16*)(w + oPMW2T);
    u16* psW1T   = (u16*)(w + oPSW1T);
    u16* psW2T   = (u16*)(w + oPSW2T);
    u16* dmW1T   = (u16*)(w + oDMW1T);
    u16* dmW2T   = (u16*)(w + oDMW2T);
    u16* HS      = (u16*)(w + oHS);
    u16* ZBF     = (u16*)(w + oZBF);
    u16* PHI     = (u16*)(w + oPHI);
    u16* GIP     = (u16*)(w + oGIP);
    u16* XbfT    = (u16*)(w + oGIP);                 // dead after phi GEMM
    float* PMbuf = (float*)(w + oGIP);               // phase C only (GIP dead)
    float* PSbuf = (float*)(w + oGIP + 33554432);
    unsigned* bar = (unsigned*)(w + oBAR);
    float* kldT  = (float*)(w + oKLDT);
    float* nllT  = (float*)(w + oNLLT);

    // ---- phase A: conversions / weight transposes / big precompute GEMMs ----
    conv_x4<<<32768, 256, 0, stream>>>(XbfT, x);
    conv_f32_bf16<<<1024, 256, 0, stream>>>(HS, h0, 262144);
    tr_conv<<<2048, 256, 0, stream>>>(phixWt, phix_w, 512, 1024, 1024);
    tr_conv<<<8192, 256, 0, stream>>>(wcatT, em_w1, 2048, 1024, 1024);
    tr_conv<<<8192, 256, 0, stream>>>(wcatT + (size_t)1024 * 2048, es_w1, 2048, 1024, 1024);
    tr_conv<<<512, 256, 0, stream>>>(emW2T, em_w2, 1024, 128, 128);
    tr_conv<<<512, 256, 0, stream>>>(esW2T, es_w2, 1024, 128, 128);
    tr_conv<<<12288, 256, 0, stream>>>(wihPhiT, gwih, 1024, 3072, 3072);
    tr_conv<<<1536, 256, 0, stream>>>(wihZT, gwih + (size_t)1024 * 3072, 128, 3072, 3072);
    tr_conv<<<4096, 256, 0, stream>>>(pmW1T, pm_w1, 1024, 1024, 1024);
    tr_conv<<<512, 256, 0, stream>>>(pmW2T, pm_w2, 1024, 128, 128);
    tr_conv<<<4096, 256, 0, stream>>>(psW1T, ps_w1, 1024, 1024, 1024);
    tr_conv<<<512, 256, 0, stream>>>(psW2T, ps_w2, 1024, 128, 128);
    tr_conv<<<4608, 256, 0, stream>>>(dmW1T, dm_w1, 1152, 1024, 1024);
    tr_conv<<<2048, 256, 0, stream>>>(dmW2T, dm_w2, 1024, 512, 512);

    // PHI = relu(x_t @ phix_w + b)  [65536, 1024]  (reads XbfT = GIP region start)
    gemm128<EPI_BF16_RELU><<<dim3(8, 512, 1), 256, 0, stream>>>(
        XbfT, nullptr, 512, 0, 512, phixWt, 512, phix_b, PHI, nullptr, 65536, 1024, 512, 512);
    // GIP = phi @ gru_wih[:H]  [65536, 3072]  (overwrites XbfT region)
    gemm128<EPI_BF16_NONE><<<dim3(24, 512, 1), 256, 0, stream>>>(
        PHI, nullptr, 1024, 0, 1024, wihPhiT, 1024, nullptr, GIP, nullptr, 65536, 3072, 1024, 1024);

    // ---- phase B: persistent sequential kernel ----
    init_ctr<<<1, 512, 0, stream>>>(bar);
    vrnn_seq<<<256, 256, 0, stream>>>(eps, em_b1, es_b1, em_b2, es_b2, gbih, gbhh,
                                      (char*)d_ws, out);

    // ---- phase C: deferred prior / decoder / loss ----
    gemm128<EPI_BF16_RELU><<<dim3(8, 512, 1), 256, 0, stream>>>(
        HS, nullptr, 1024, 0, 1024, pmW1T, 1024, pm_b1, PHI, nullptr, 65536, 1024, 1024, 1024);
    gemm128<EPI_F32_RELU><<<dim3(1, 512, 1), 256, 0, stream>>>(
        PHI, nullptr, 1024, 0, 1024, pmW2T, 1024, pm_b2, nullptr, PMbuf, 65536, 128, 1024, 1024);
    gemm128<EPI_BF16_RELU><<<dim3(8, 512, 1), 256, 0, stream>>>(
        HS, nullptr, 1024, 0, 1024, psW1T, 1024, ps_b1, PHI, nullptr, 65536, 1024, 1024, 1024);
    gemm128<EPI_F32_SP><<<dim3(1, 512, 1), 256, 0, stream>>>(
        PHI, nullptr, 1024, 0, 1024, psW2T, 1024, ps_b2, nullptr, PSbuf, 65536, 128, 1024, 1024);
    gemm128<EPI_BF16_RELU><<<dim3(8, 512, 1), 256, 0, stream>>>(
        HS, ZBF, 1024, 128, 1024, dmW1T, 1152, dm_b1, PHI, nullptr, 65536, 1024, 1152, 1152);
    gemm128<EPI_F32_SIG><<<dim3(4, 512, 1), 256, 0, stream>>>(
        PHI, nullptr, 1024, 0, 1024, dmW2T, 1024, dm_b2, nullptr, out + O_XM, 65536, 512, 1024, 1024);

    loss_per_t<<<256, 256, 0, stream>>>(x, out + O_XM, out + O_MU, out + O_STD,
                                        PMbuf, PSbuf, kldT, nllT);
    loss_final<<<1, 256, 0, stream>>>(kldT, nllT, out);
}

// Round 4
// 51364.221 us; speedup vs baseline: 5.6529x; 5.6529x over previous
//
#include <hip/hip_runtime.h>

typedef unsigned short u16;
typedef __bf16 bf16x8 __attribute__((ext_vector_type(8)));
typedef float f32x4 __attribute__((ext_vector_type(4)));

#define EPSC 1e-6f

// ---------- helpers ----------
__device__ __forceinline__ float b2f(u16 x) { return __uint_as_float(((unsigned)x) << 16); }
__device__ __forceinline__ u16 f2b(float f) {
    unsigned u = __float_as_uint(f);
    unsigned r = (u + 0x7fffu + ((u >> 16) & 1u)) >> 16;
    return (u16)r;
}
__device__ __forceinline__ float softplusf(float x) {
    return fmaxf(x, 0.f) + log1pf(__expf(-fabsf(x)));
}

// ---------- conversion / transpose kernels ----------
__global__ void conv_x4(u16* __restrict__ dst, const float* __restrict__ x) {
    size_t i4 = (size_t)blockIdx.x * 256 + threadIdx.x;
    size_t o = i4 * 4;
    int d = (int)(o & 511);
    int b = (int)((o >> 9) & 255);
    int t = (int)(o >> 17);
    float4 v = *(const float4*)(x + ((size_t)b * 256 + t) * 512 + d);
    unsigned p0 = (unsigned)f2b(v.x) | ((unsigned)f2b(v.y) << 16);
    unsigned p1 = (unsigned)f2b(v.z) | ((unsigned)f2b(v.w) << 16);
    *(uint2*)(dst + o) = make_uint2(p0, p1);
}

__global__ void conv_f32_bf16(u16* __restrict__ dst, const float* __restrict__ src, int n) {
    int i = blockIdx.x * 256 + threadIdx.x;
    if (i < n) dst[i] = f2b(src[i]);
}

__global__ void tr_conv(u16* __restrict__ dst, const float* __restrict__ src,
                        int R, int C, int ld) {
    int idx = blockIdx.x * 256 + threadIdx.x;
    if (idx >= R * C) return;
    int c = idx / R, r = idx % R;
    dst[idx] = f2b(src[(size_t)r * ld + c]);
}

__global__ void init_ctr(unsigned* bar) {
    if (threadIdx.x < 512) bar[threadIdx.x] = 0u;
}

// ---------- generic 128x128 bf16 MFMA GEMM (phase A/C) ----------
enum { EPI_PARTIAL = 0, EPI_BF16_RELU = 1, EPI_BF16_NONE = 2,
       EPI_F32_RELU = 3, EPI_F32_SP = 4, EPI_F32_SIG = 5 };

template <int EPI>
__global__ __launch_bounds__(256)
void gemm128(const u16* __restrict__ A0, const u16* __restrict__ A1,
             int lda0, int lda1, int kSplit,
             const u16* __restrict__ Wt, int ldw,
             const float* __restrict__ bias,
             u16* __restrict__ Cb, float* __restrict__ Cf,
             int M, int N, int K, int kChunk) {
    __shared__ __align__(16) u16 As[128 * 72];
    __shared__ __align__(16) u16 Bs[128 * 72];
    const int tid = threadIdx.x;
    const int wid = tid >> 6, lane = tid & 63;
    const int wm = wid >> 1, wn = wid & 1;
    const int lr = lane & 15, lk = lane >> 4;
    const int m0 = blockIdx.y * 128, n0 = blockIdx.x * 128;
    const int kBeg = blockIdx.z * kChunk;
    const int rsub = lane >> 3;
    const int csub = (lane & 7) * 8;

    f32x4 acc[4][4];
#pragma unroll
    for (int i = 0; i < 4; i++)
#pragma unroll
        for (int j = 0; j < 4; j++) { f32x4 z = {0.f, 0.f, 0.f, 0.f}; acc[i][j] = z; }

    for (int kt = 0; kt < kChunk; kt += 64) {
        const int k0 = kBeg + kt;
        const u16* Ap; int kk, lda;
        if (k0 < kSplit) { Ap = A0; kk = k0; lda = lda0; }
        else             { Ap = A1; kk = k0 - kSplit; lda = lda1; }
        uint4 ra[4], rb[4];
#pragma unroll
        for (int i = 0; i < 4; i++) {
            const int q = wid * 4 + i;
            const int r = q * 8 + rsub;
            ra[i] = *(const uint4*)(Ap + (size_t)(m0 + r) * lda + kk + csub);
            rb[i] = *(const uint4*)(Wt + (size_t)(n0 + r) * ldw + k0 + csub);
        }
        __syncthreads();
#pragma unroll
        for (int i = 0; i < 4; i++) {
            const int q = wid * 4 + i;
            const int r = q * 8 + rsub;
            *(uint4*)&As[r * 72 + csub] = ra[i];
            *(uint4*)&Bs[r * 72 + csub] = rb[i];
        }
        __syncthreads();
#pragma unroll
        for (int s = 0; s < 2; s++) {
            bf16x8 af[4], bfr[4];
#pragma unroll
            for (int i = 0; i < 4; i++)
                af[i] = *(const bf16x8*)&As[(wm * 64 + i * 16 + lr) * 72 + s * 32 + lk * 8];
#pragma unroll
            for (int j = 0; j < 4; j++)
                bfr[j] = *(const bf16x8*)&Bs[(wn * 64 + j * 16 + lr) * 72 + s * 32 + lk * 8];
#pragma unroll
            for (int i = 0; i < 4; i++)
#pragma unroll
                for (int j = 0; j < 4; j++)
                    acc[i][j] = __builtin_amdgcn_mfma_f32_16x16x32_bf16(af[i], bfr[j], acc[i][j], 0, 0, 0);
        }
    }

    const int rowb = m0 + wm * 64, colb = n0 + wn * 64;
#pragma unroll
    for (int i = 0; i < 4; i++) {
#pragma unroll
        for (int j = 0; j < 4; j++) {
            const int col = colb + j * 16 + lr;
#pragma unroll
            for (int r = 0; r < 4; r++) {
                const int row = rowb + i * 16 + lk * 4 + r;
                float v = acc[i][j][r];
                if (EPI == EPI_PARTIAL) {
                    Cf[(size_t)blockIdx.z * ((size_t)M * N) + (size_t)row * N + col] = v;
                } else {
                    if (bias) v += bias[col];
                    if (EPI == EPI_BF16_RELU || EPI == EPI_F32_RELU) v = fmaxf(v, 0.f);
                    else if (EPI == EPI_F32_SP)  v = softplusf(v);
                    else if (EPI == EPI_F32_SIG) v = 1.f / (1.f + __expf(-v));
                    if (EPI == EPI_BF16_RELU || EPI == EPI_BF16_NONE) Cb[(size_t)row * N + col] = f2b(v);
                    else Cf[(size_t)row * N + col] = v;
                }
            }
        }
    }
}

// ---------- workspace layout (bytes) ----------
static constexpr size_t oPHIXWT  = 0;                      // [1024][512]
static constexpr size_t oWCATT   = 1048576;                // [2048][2048]
static constexpr size_t oEMW2T   = 9437184;                // [128][1024]
static constexpr size_t oESW2T   = 9699328;
static constexpr size_t oWIHPHIT = 9961472;                // [3072][1024]
static constexpr size_t oWIHZT   = 16252928;               // [3072][128]
static constexpr size_t oPMW1T   = 17039360;
static constexpr size_t oPMW2T   = 19136512;
static constexpr size_t oPSW1T   = 19398656;
static constexpr size_t oPSW2T   = 21495808;
static constexpr size_t oDMW1T   = 21757952;               // [1024][1152]
static constexpr size_t oDMW2T   = 24117248;               // [512][1024]
static constexpr size_t oHS      = 25165824;               // [T+1][B][H] bf16
static constexpr size_t oZBF     = 159907840;              // [T][B][Z] bf16
static constexpr size_t oT12     = 176685056;              // [256][2048] bf16
static constexpr size_t oBAR     = 177733632;              // 512 uints (slots[256] + masters)
static constexpr size_t oKLDT    = 177737728;
static constexpr size_t oNLLT    = 177738752;
static constexpr size_t oPHI     = 177739776;              // [65536][1024] bf16 (U1 in phase C)
static constexpr size_t oGIP     = 311957504;              // [65536][3072] bf16 (XbfT / PM / PS overlay)
static constexpr size_t WS_NEED  = 714610688;

static constexpr size_t NZ = (size_t)256 * 256 * 128;
static constexpr size_t O_Z  = 3;
static constexpr size_t O_MU = 3 + NZ;
static constexpr size_t O_STD = 3 + 2 * NZ;
static constexpr size_t O_XM = 3 + 3 * NZ;

// ---------- grid barrier: relaxed-spin flag array (NO acquire in spin loops) ----------
__device__ __forceinline__ void gbar(unsigned* slots, unsigned* master, unsigned n) {
    __syncthreads();                 // drains vmcnt: all block's stores are in L2
    const int bx = blockIdx.x, tid = threadIdx.x;
    if (tid == 0) {
        __threadfence();             // one-time L2 writeback (release)
        __hip_atomic_store(&slots[bx], n, __ATOMIC_RELAXED, __HIP_MEMORY_SCOPE_AGENT);
    }
    if (bx == 0) {
        if (tid > 0) {               // 255 threads poll 255 slots, relaxed only
            while (__hip_atomic_load(&slots[tid], __ATOMIC_RELAXED, __HIP_MEMORY_SCOPE_AGENT) < n)
                __builtin_amdgcn_s_sleep(2);
        }
        __syncthreads();
        if (tid < 8)                 // publish to 8 replicated master lines
            __hip_atomic_store(&master[tid * 16], n, __ATOMIC_RELAXED, __HIP_MEMORY_SCOPE_AGENT);
        if (tid == 0) __threadfence();  // one-time invalidate (acquire)
        __syncthreads();
    } else {
        if (tid == 0) {
            while (__hip_atomic_load(&master[(bx & 7) * 16], __ATOMIC_RELAXED, __HIP_MEMORY_SCOPE_AGENT) < n)
                __builtin_amdgcn_s_sleep(2);
            __threadfence();         // one-time invalidate (acquire)
        }
        __syncthreads();
    }
}

// ---------- persistent sequential-phase kernel ----------
__global__ __launch_bounds__(256)
void vrnn_seq(const float* __restrict__ eps,
              const float* __restrict__ em_b1, const float* __restrict__ es_b1,
              const float* __restrict__ em_b2, const float* __restrict__ es_b2,
              const float* __restrict__ gbih, const float* __restrict__ gbhh,
              char* ws, float* out) {
    __shared__ __align__(16) u16 SA[128 * 72];
    __shared__ __align__(16) u16 SB[128 * 72];
    __shared__ float zsL[16 * 32];

    const int bx = blockIdx.x, tid = threadIdx.x;
    const int wid = tid >> 6, lane = tid & 63;
    const int lr = lane & 15, lk = lane >> 4;
    const int wm = wid >> 1, wn = wid & 1;
    const int sr = tid >> 3, sc = (tid & 7) * 8;

    const u16* wcatT = (const u16*)(ws + oWCATT);
    const u16* emW2T = (const u16*)(ws + oEMW2T);
    const u16* esW2T = (const u16*)(ws + oESW2T);
    const u16* wihZT = (const u16*)(ws + oWIHZT);
    const u16* PHI   = (const u16*)(ws + oPHI);
    const u16* GIP   = (const u16*)(ws + oGIP);
    u16* HS   = (u16*)(ws + oHS);
    u16* ZBFg = (u16*)(ws + oZBF);
    u16* T12g = (u16*)(ws + oT12);
    unsigned* slots  = (unsigned*)(ws + oBAR);
    unsigned* master = slots + 256;

    float* outZ  = out + O_Z;
    float* outMu = out + O_MU;
    float* outSd = out + O_STD;

    unsigned nb = 0;

#define W1_LOAD(RA, RB, KT) {                                                        \
    const int k0_ = (KT) * 64;                                                       \
    const u16* Ap_ = (k0_ < 1024) ? A0t : A1t;                                       \
    const int kk_ = (k0_ < 1024) ? k0_ : k0_ - 1024;                                 \
    _Pragma("unroll")                                                                \
    for (int i_ = 0; i_ < 4; i_++)                                                   \
        RA[i_] = *(const uint4*)(Ap_ + (size_t)(mI*128 + i_*32 + sr) * 1024 + kk_ + sc); \
    _Pragma("unroll")                                                                \
    for (int i_ = 0; i_ < 4; i_++)                                                   \
        RB[i_] = *(const uint4*)(Bb + (size_t)(i_*32 + sr) * 2048 + k0_ + sc);       \
}

#define W1_STAGE(RA, RB) {                                                           \
    __syncthreads();                                                                 \
    _Pragma("unroll")                                                                \
    for (int i_ = 0; i_ < 4; i_++) *(uint4*)&SA[(i_*32 + sr) * 72 + sc] = RA[i_];    \
    _Pragma("unroll")                                                                \
    for (int i_ = 0; i_ < 4; i_++) *(uint4*)&SB[(i_*32 + sr) * 72 + sc] = RB[i_];    \
    __syncthreads();                                                                 \
}

#define W1_MFMA() {                                                                  \
    _Pragma("unroll")                                                                \
    for (int s_ = 0; s_ < 2; s_++) {                                                 \
        bf16x8 af_[4], bf_[4];                                                       \
        _Pragma("unroll")                                                            \
        for (int i_ = 0; i_ < 4; i_++)                                               \
            af_[i_] = *(const bf16x8*)&SA[(wm*64 + i_*16 + lr) * 72 + s_*32 + lk*8]; \
        _Pragma("unroll")                                                            \
        for (int j_ = 0; j_ < 4; j_++)                                               \
            bf_[j_] = *(const bf16x8*)&SB[(wn*64 + j_*16 + lr) * 72 + s_*32 + lk*8]; \
        _Pragma("unroll")                                                            \
        for (int i_ = 0; i_ < 4; i_++)                                               \
            _Pragma("unroll")                                                        \
            for (int j_ = 0; j_ < 4; j_++)                                           \
                acc[i_][j_] = __builtin_amdgcn_mfma_f32_16x16x32_bf16(af_[i_], bf_[j_], acc[i_][j_], 0, 0, 0); \
    }                                                                                \
}

#pragma unroll 1
    for (int t = 0; t < 256; t++) {
        // ======== window 1: T12 = [h_t | phi_t] @ wcat  (blocks 0..31, 128x128 tiles) ========
        if (bx < 32) {
            const int mI = bx & 1, nI = bx >> 1;
            const u16* Bb  = wcatT + (size_t)(nI * 128) * 2048;
            const u16* A0t = HS  + (size_t)t * 262144;
            const u16* A1t = PHI + (size_t)t * 262144;
            f32x4 acc[4][4];
#pragma unroll
            for (int i = 0; i < 4; i++)
#pragma unroll
                for (int j = 0; j < 4; j++) { f32x4 z = {0.f,0.f,0.f,0.f}; acc[i][j] = z; }
            uint4 ra0[4], rb0[4], ra1[4], rb1[4];
            W1_LOAD(ra0, rb0, 0);
            W1_LOAD(ra1, rb1, 1);
#pragma unroll 1
            for (int kt = 0; kt < 32; kt += 2) {
                W1_STAGE(ra0, rb0);
                if (kt + 2 < 32) W1_LOAD(ra0, rb0, kt + 2);
                W1_MFMA();
                W1_STAGE(ra1, rb1);
                if (kt + 3 < 32) W1_LOAD(ra1, rb1, kt + 3);
                W1_MFMA();
            }
#pragma unroll
            for (int a = 0; a < 4; a++)
#pragma unroll
                for (int b = 0; b < 4; b++) {
                    const int col = nI*128 + wn*64 + b*16 + lr;
                    const float bb = (col < 1024) ? em_b1[col] : es_b1[col - 1024];
#pragma unroll
                    for (int r = 0; r < 4; r++) {
                        const int row = mI*128 + wm*64 + a*16 + lk*4 + r;
                        T12g[(size_t)row * 2048 + col] = f2b(fmaxf(acc[a][b][r] + bb, 0.f));
                    }
                }
        }
        gbar(slots, master, ++nb);

        // ======== window 2: zm/zs -> z  (blocks 0..63: 16 rows x 32 z-cols each) ========
        if (bx < 64) {
            const int rg = bx >> 2, cg = bx & 3, r0 = rg * 16;
            const int half = wid & 1, csel = wid >> 1;
            const int c0 = cg * 32 + csel * 16;          // z-col base for this wave
            const u16* W2T  = half ? esW2T : emW2T;
            const u16* Arow = T12g + (size_t)(r0 + lr) * 2048 + half * 1024;
            const u16* Brow = W2T + (size_t)(c0 + lr) * 1024;
            f32x4 a4 = {0.f, 0.f, 0.f, 0.f};
#pragma unroll 8
            for (int ks = 0; ks < 32; ks++) {
                bf16x8 af = *(const bf16x8*)(Arow + ks*32 + lk*8);
                bf16x8 bf = *(const bf16x8*)(Brow + ks*32 + lk*8);
                a4 = __builtin_amdgcn_mfma_f32_16x16x32_bf16(af, bf, a4, 0, 0, 0);
            }
            const int colz = c0 + lr;                    // 0..127 (z-space)
            if (half) {                                  // zs -> LDS
#pragma unroll
                for (int r = 0; r < 4; r++)
                    zsL[(lk*4 + r) * 32 + (csel*16 + lr)] = softplusf(a4[r] + es_b2[colz]);
            }
            __syncthreads();
            if (!half) {                                 // zm in regs, zs from LDS
#pragma unroll
                for (int r = 0; r < 4; r++) {
                    const int row = lk*4 + r;
                    const float zm = fmaxf(a4[r] + em_b2[colz], 0.f);
                    const float zs = zsL[row * 32 + (csel*16 + lr)];
                    const size_t o = (size_t)t*32768 + (size_t)(r0 + row)*128 + colz;
                    const float z = zm + zs * eps[o];
                    outMu[o] = zm; outSd[o] = zs; outZ[o] = z;
                    ZBFg[o] = f2b(z);
                }
            }
        }
        gbar(slots, master, ++nb);

        // ======== window 3: GRU -> h_{t+1}  (blocks 0..127: 16 rows x 128 h-cols each) ========
        if (bx < 128) {
            const int rg = bx >> 3, cg = bx & 7, r0 = rg * 16;
            bf16x8 zf[4];
            const u16* zrow = ZBFg + (size_t)t*32768 + (size_t)(r0 + lr)*128;
#pragma unroll
            for (int ks = 0; ks < 4; ks++) zf[ks] = *(const bf16x8*)(zrow + ks*32 + lk*8);
            const u16* gipt = GIP + (size_t)t * 786432;   // [256][3072]
            u16* HSn = HS + (size_t)(t+1) * 262144;
#pragma unroll
            for (int jj = 0; jj < 2; jj++) {
                const int jt = cg*8 + wid*2 + jj;        // col-tile 0..63
                const int col = jt*16 + lr;              // 0..1023
                f32x4 aR = {0.f,0.f,0.f,0.f}, aU = {0.f,0.f,0.f,0.f}, aN = {0.f,0.f,0.f,0.f};
#pragma unroll
                for (int ks = 0; ks < 4; ks++) {
                    const int ko = ks*32 + lk*8;
                    bf16x8 bR = *(const bf16x8*)(wihZT + (size_t)(       col)*128 + ko);
                    bf16x8 bU = *(const bf16x8*)(wihZT + (size_t)(1024 + col)*128 + ko);
                    bf16x8 bN = *(const bf16x8*)(wihZT + (size_t)(2048 + col)*128 + ko);
                    aR = __builtin_amdgcn_mfma_f32_16x16x32_bf16(zf[ks], bR, aR, 0, 0, 0);
                    aU = __builtin_amdgcn_mfma_f32_16x16x32_bf16(zf[ks], bU, aU, 0, 0, 0);
                    aN = __builtin_amdgcn_mfma_f32_16x16x32_bf16(zf[ks], bN, aN, 0, 0, 0);
                }
                const float bihR = gbih[col],        bhR = gbhh[col];
                const float bihU = gbih[1024 + col], bhU = gbhh[1024 + col];
                const float bihN = gbih[2048 + col], bhN = gbhh[2048 + col];
#pragma unroll
                for (int r = 0; r < 4; r++) {
                    const int b = r0 + lk*4 + r;
                    const u16* gp = gipt + (size_t)b * 3072;
                    const float gr = aR[r] + b2f(gp[col])        + bihR + bhR;
                    const float gu = aU[r] + b2f(gp[1024 + col]) + bihU + bhU;
                    float gn       = aN[r] + b2f(gp[2048 + col]) + bihN;
                    const float rr_ = 1.f / (1.f + __expf(-gr));
                    const float uu  = 1.f / (1.f + __expf(-gu));
                    gn += rr_ * bhN;
                    const float e2 = __expf(-2.f * fabsf(gn));
                    float th = (1.f - e2) / (1.f + e2);
                    th = (gn < 0.f) ? -th : th;
                    HSn[(size_t)b * 1024 + col] = f2b((1.f - uu) * th);
                }
            }
        }
        gbar(slots, master, ++nb);
    }
#undef W1_LOAD
#undef W1_STAGE
#undef W1_MFMA
}

// ---------- loss ----------
__global__ __launch_bounds__(256)
void loss_per_t(const float* __restrict__ x,
                const float* __restrict__ xm,
                const float* __restrict__ zm, const float* __restrict__ zs,
                const float* __restrict__ pm, const float* __restrict__ ps,
                float* __restrict__ kldT, float* __restrict__ nllT) {
    const int t = blockIdx.x, bb = threadIdx.x;
    float kld = 0.f, nll = 0.f;
    const size_t ozb = ((size_t)t * 256 + bb) * 128;
    for (int zz = 0; zz < 128; zz++) {
        const float qs = zs[ozb + zz], qm = zm[ozb + zz];
        const float pmv = pm[ozb + zz], psv = ps[ozb + zz];
        const float d = qm - pmv;
        kld += logf(psv + EPSC) - logf(qs + EPSC)
             + (qs * qs + d * d) / (2.f * psv * psv + EPSC) - 0.5f;
    }
    const size_t oxb = ((size_t)t * 256 + bb) * 512;
    const size_t oxi = ((size_t)bb * 256 + t) * 512;
    for (int dd = 0; dd < 512; dd++) {
        const float xv = x[oxi + dd];
        float m = xm[oxb + dd];
        m = fminf(fmaxf(m, 1e-6f), 1.f - 1e-6f);
        nll -= xv * logf(m) + (1.f - xv) * log1pf(-m);
    }
    __shared__ float sk[256], sn[256];
    sk[bb] = kld; sn[bb] = nll;
    __syncthreads();
    for (int s = 128; s > 0; s >>= 1) {
        if (bb < s) { sk[bb] += sk[bb + s]; sn[bb] += sn[bb + s]; }
        __syncthreads();
    }
    if (bb == 0) { kldT[t] = sk[0] / 256.f; nllT[t] = sn[0] / 256.f; }
}

__global__ __launch_bounds__(256)
void loss_final(const float* __restrict__ kldT, const float* __restrict__ nllT,
                float* __restrict__ out) {
    const int tid = threadIdx.x;
    __shared__ float s[256];
    s[tid] = kldT[tid] + nllT[tid];
    __syncthreads();
    for (int st = 128; st > 0; st >>= 1) {
        if (tid < st) s[tid] += s[tid + st];
        __syncthreads();
    }
    if (tid == 0) { out[0] = s[0]; out[1] = kldT[255]; out[2] = nllT[255]; }
}

extern "C" void kernel_launch(void* const* d_in, const int* in_sizes, int n_in,
                              void* d_out, int out_size, void* d_ws, size_t ws_size,
                              hipStream_t stream) {
    const float* x      = (const float*)d_in[0];
    const float* eps    = (const float*)d_in[1];
    const float* h0     = (const float*)d_in[2];
    const float* phix_w = (const float*)d_in[3];
    const float* phix_b = (const float*)d_in[4];
    const float* pm_w1  = (const float*)d_in[5];
    const float* pm_b1  = (const float*)d_in[6];
    const float* pm_w2  = (const float*)d_in[7];
    const float* pm_b2  = (const float*)d_in[8];
    const float* ps_w1  = (const float*)d_in[9];
    const float* ps_b1  = (const float*)d_in[10];
    const float* ps_w2  = (const float*)d_in[11];
    const float* ps_b2  = (const float*)d_in[12];
    const float* em_w1  = (const float*)d_in[13];
    const float* em_b1  = (const float*)d_in[14];
    const float* em_w2  = (const float*)d_in[15];
    const float* em_b2  = (const float*)d_in[16];
    const float* es_w1  = (const float*)d_in[17];
    const float* es_b1  = (const float*)d_in[18];
    const float* es_w2  = (const float*)d_in[19];
    const float* es_b2  = (const float*)d_in[20];
    const float* dm_w1  = (const float*)d_in[21];
    const float* dm_b1  = (const float*)d_in[22];
    const float* dm_w2  = (const float*)d_in[23];
    const float* dm_b2  = (const float*)d_in[24];
    const float* gwih   = (const float*)d_in[25];
    const float* gbih   = (const float*)d_in[26];
    const float* gbhh   = (const float*)d_in[27];
    float* out = (float*)d_out;

    if (ws_size < WS_NEED) return;
    char* w = (char*)d_ws;
    u16* phixWt  = (u16*)(w + oPHIXWT);
    u16* wcatT   = (u16*)(w + oWCATT);
    u16* emW2T   = (u16*)(w + oEMW2T);
    u16* esW2T   = (u16*)(w + oESW2T);
    u16* wihPhiT = (u16*)(w + oWIHPHIT);
    u16* wihZT   = (u16*)(w + oWIHZT);
    u16* pmW1T   = (u16*)(w + oPMW1T);
    u16* pmW2T   = (u16*)(w + oPMW2T);
    u16* psW1T   = (u16*)(w + oPSW1T);
    u16* psW2T   = (u16*)(w + oPSW2T);
    u16* dmW1T   = (u16*)(w + oDMW1T);
    u16* dmW2T   = (u16*)(w + oDMW2T);
    u16* HS      = (u16*)(w + oHS);
    u16* ZBF     = (u16*)(w + oZBF);
    u16* PHI     = (u16*)(w + oPHI);
    u16* GIP     = (u16*)(w + oGIP);
    u16* XbfT    = (u16*)(w + oGIP);                 // dead after phi GEMM
    float* PMbuf = (float*)(w + oGIP);               // phase C only (GIP dead)
    float* PSbuf = (float*)(w + oGIP + 33554432);
    unsigned* bar = (unsigned*)(w + oBAR);
    float* kldT  = (float*)(w + oKLDT);
    float* nllT  = (float*)(w + oNLLT);

    // ---- phase A: conversions / weight transposes / big precompute GEMMs ----
    conv_x4<<<32768, 256, 0, stream>>>(XbfT, x);
    conv_f32_bf16<<<1024, 256, 0, stream>>>(HS, h0, 262144);
    tr_conv<<<2048, 256, 0, stream>>>(phixWt, phix_w, 512, 1024, 1024);
    tr_conv<<<8192, 256, 0, stream>>>(wcatT, em_w1, 2048, 1024, 1024);
    tr_conv<<<8192, 256, 0, stream>>>(wcatT + (size_t)1024 * 2048, es_w1, 2048, 1024, 1024);
    tr_conv<<<512, 256, 0, stream>>>(emW2T, em_w2, 1024, 128, 128);
    tr_conv<<<512, 256, 0, stream>>>(esW2T, es_w2, 1024, 128, 128);
    tr_conv<<<12288, 256, 0, stream>>>(wihPhiT, gwih, 1024, 3072, 3072);
    tr_conv<<<1536, 256, 0, stream>>>(wihZT, gwih + (size_t)1024 * 3072, 128, 3072, 3072);
    tr_conv<<<4096, 256, 0, stream>>>(pmW1T, pm_w1, 1024, 1024, 1024);
    tr_conv<<<512, 256, 0, stream>>>(pmW2T, pm_w2, 1024, 128, 128);
    tr_conv<<<4096, 256, 0, stream>>>(psW1T, ps_w1, 1024, 1024, 1024);
    tr_conv<<<512, 256, 0, stream>>>(psW2T, ps_w2, 1024, 128, 128);
    tr_conv<<<4608, 256, 0, stream>>>(dmW1T, dm_w1, 1152, 1024, 1024);
    tr_conv<<<2048, 256, 0, stream>>>(dmW2T, dm_w2, 1024, 512, 512);

    // PHI = relu(x_t @ phix_w + b)  [65536, 1024]  (reads XbfT = GIP region start)
    gemm128<EPI_BF16_RELU><<<dim3(8, 512, 1), 256, 0, stream>>>(
        XbfT, nullptr, 512, 0, 512, phixWt, 512, phix_b, PHI, nullptr, 65536, 1024, 512, 512);
    // GIP = phi @ gru_wih[:H]  [65536, 3072]  (overwrites XbfT region)
    gemm128<EPI_BF16_NONE><<<dim3(24, 512, 1), 256, 0, stream>>>(
        PHI, nullptr, 1024, 0, 1024, wihPhiT, 1024, nullptr, GIP, nullptr, 65536, 3072, 1024, 1024);

    // ---- phase B: persistent sequential kernel ----
    init_ctr<<<1, 512, 0, stream>>>(bar);
    vrnn_seq<<<256, 256, 0, stream>>>(eps, em_b1, es_b1, em_b2, es_b2, gbih, gbhh,
                                      (char*)d_ws, out);

    // ---- phase C: deferred prior / decoder / loss ----
    gemm128<EPI_BF16_RELU><<<dim3(8, 512, 1), 256, 0, stream>>>(
        HS, nullptr, 1024, 0, 1024, pmW1T, 1024, pm_b1, PHI, nullptr, 65536, 1024, 1024, 1024);
    gemm128<EPI_F32_RELU><<<dim3(1, 512, 1), 256, 0, stream>>>(
        PHI, nullptr, 1024, 0, 1024, pmW2T, 1024, pm_b2, nullptr, PMbuf, 65536, 128, 1024, 1024);
    gemm128<EPI_BF16_RELU><<<dim3(8, 512, 1), 256, 0, stream>>>(
        HS, nullptr, 1024, 0, 1024, psW1T, 1024, ps_b1, PHI, nullptr, 65536, 1024, 1024, 1024);
    gemm128<EPI_F32_SP><<<dim3(1, 512, 1), 256, 0, stream>>>(
        PHI, nullptr, 1024, 0, 1024, psW2T, 1024, ps_b2, nullptr, PSbuf, 65536, 128, 1024, 1024);
    gemm128<EPI_BF16_RELU><<<dim3(8, 512, 1), 256, 0, stream>>>(
        HS, ZBF, 1024, 128, 1024, dmW1T, 1152, dm_b1, PHI, nullptr, 65536, 1024, 1152, 1152);
    gemm128<EPI_F32_SIG><<<dim3(4, 512, 1), 256, 0, stream>>>(
        PHI, nullptr, 1024, 0, 1024, dmW2T, 1024, dm_b2, nullptr, out + O_XM, 65536, 512, 1024, 1024);

    loss_per_t<<<256, 256, 0, stream>>>(x, out + O_XM, out + O_MU, out + O_STD,
                                        PMbuf, PSbuf, kldT, nllT);
    loss_final<<<1, 256, 0, stream>>>(kldT, nllT, out);
}

// Round 6
// 27381.393 us; speedup vs baseline: 10.6042x; 1.8759x over previous
//
#include <hip/hip_runtime.h>

typedef unsigned short u16;
typedef __bf16 bf16x8 __attribute__((ext_vector_type(8)));
typedef float f32x4 __attribute__((ext_vector_type(4)));

#define EPSC 1e-6f

// ---------- helpers ----------
__device__ __forceinline__ float b2f(u16 x) { return __uint_as_float(((unsigned)x) << 16); }
__device__ __forceinline__ u16 f2b(float f) {
    unsigned u = __float_as_uint(f);
    unsigned r = (u + 0x7fffu + ((u >> 16) & 1u)) >> 16;
    return (u16)r;
}
__device__ __forceinline__ float softplusf(float x) {
    return fmaxf(x, 0.f) + log1pf(__expf(-fabsf(x)));
}

// coherent (cross-XCD) access via per-instruction cache policy (sc1):
// relaxed agent-scope atomics write through / bypass the per-XCD caches to the
// IC coherence point. No cache-maintenance (inv/wb) instructions anywhere.
__device__ __forceinline__ void st_cg16(void* p, uint4 v) {
    unsigned long long lo = (unsigned long long)v.x | ((unsigned long long)v.y << 32);
    unsigned long long hi = (unsigned long long)v.z | ((unsigned long long)v.w << 32);
    __hip_atomic_store((unsigned long long*)p,     lo, __ATOMIC_RELAXED, __HIP_MEMORY_SCOPE_AGENT);
    __hip_atomic_store((unsigned long long*)p + 1, hi, __ATOMIC_RELAXED, __HIP_MEMORY_SCOPE_AGENT);
}
__device__ __forceinline__ void st_cg2(void* p, unsigned v) {
    __hip_atomic_store((unsigned short*)p, (unsigned short)v,
                       __ATOMIC_RELAXED, __HIP_MEMORY_SCOPE_AGENT);
}
__device__ __forceinline__ uint2 ld_cg8(const void* p) {
    unsigned long long v = __hip_atomic_load((const unsigned long long*)p,
                                             __ATOMIC_RELAXED, __HIP_MEMORY_SCOPE_AGENT);
    uint2 r; r.x = (unsigned)v; r.y = (unsigned)(v >> 32);
    return r;
}
__device__ __forceinline__ bf16x8 mk8(uint2 a, uint2 b) {
    uint4 u; u.x = a.x; u.y = a.y; u.z = b.x; u.w = b.y;
    return __builtin_bit_cast(bf16x8, u);
}

// ---------- conversion / transpose kernels ----------
__global__ void conv_x4(u16* __restrict__ dst, const float* __restrict__ x) {
    size_t i4 = (size_t)blockIdx.x * 256 + threadIdx.x;
    size_t o = i4 * 4;
    int d = (int)(o & 511);
    int b = (int)((o >> 9) & 255);
    int t = (int)(o >> 17);
    float4 v = *(const float4*)(x + ((size_t)b * 256 + t) * 512 + d);
    unsigned p0 = (unsigned)f2b(v.x) | ((unsigned)f2b(v.y) << 16);
    unsigned p1 = (unsigned)f2b(v.z) | ((unsigned)f2b(v.w) << 16);
    *(uint2*)(dst + o) = make_uint2(p0, p1);
}

__global__ void conv_f32_bf16(u16* __restrict__ dst, const float* __restrict__ src, int n) {
    int i = blockIdx.x * 256 + threadIdx.x;
    if (i < n) dst[i] = f2b(src[i]);
}

__global__ void tr_conv(u16* __restrict__ dst, const float* __restrict__ src,
                        int R, int C, int ld) {
    int idx = blockIdx.x * 256 + threadIdx.x;
    if (idx >= R * C) return;
    int c = idx / R, r = idx % R;
    dst[idx] = f2b(src[(size_t)r * ld + c]);
}

__global__ void init_ctr(unsigned* bar) {
    if (threadIdx.x < 512) bar[threadIdx.x] = 0u;
}

// ---------- generic 128x128 bf16 MFMA GEMM (phase A/C) ----------
enum { EPI_PARTIAL = 0, EPI_BF16_RELU = 1, EPI_BF16_NONE = 2,
       EPI_F32_RELU = 3, EPI_F32_SP = 4, EPI_F32_SIG = 5 };

template <int EPI>
__global__ __launch_bounds__(256)
void gemm128(const u16* __restrict__ A0, const u16* __restrict__ A1,
             int lda0, int lda1, int kSplit,
             const u16* __restrict__ Wt, int ldw,
             const float* __restrict__ bias,
             u16* __restrict__ Cb, float* __restrict__ Cf,
             int M, int N, int K, int kChunk) {
    __shared__ __align__(16) u16 As[128 * 72];
    __shared__ __align__(16) u16 Bs[128 * 72];
    const int tid = threadIdx.x;
    const int wid = tid >> 6, lane = tid & 63;
    const int wm = wid >> 1, wn = wid & 1;
    const int lr = lane & 15, lk = lane >> 4;
    const int m0 = blockIdx.y * 128, n0 = blockIdx.x * 128;
    const int kBeg = blockIdx.z * kChunk;
    const int rsub = lane >> 3;
    const int csub = (lane & 7) * 8;

    f32x4 acc[4][4];
#pragma unroll
    for (int i = 0; i < 4; i++)
#pragma unroll
        for (int j = 0; j < 4; j++) { f32x4 z = {0.f, 0.f, 0.f, 0.f}; acc[i][j] = z; }

    for (int kt = 0; kt < kChunk; kt += 64) {
        const int k0 = kBeg + kt;
        const u16* Ap; int kk, lda;
        if (k0 < kSplit) { Ap = A0; kk = k0; lda = lda0; }
        else             { Ap = A1; kk = k0 - kSplit; lda = lda1; }
        uint4 ra[4], rb[4];
#pragma unroll
        for (int i = 0; i < 4; i++) {
            const int q = wid * 4 + i;
            const int r = q * 8 + rsub;
            ra[i] = *(const uint4*)(Ap + (size_t)(m0 + r) * lda + kk + csub);
            rb[i] = *(const uint4*)(Wt + (size_t)(n0 + r) * ldw + k0 + csub);
        }
        __syncthreads();
#pragma unroll
        for (int i = 0; i < 4; i++) {
            const int q = wid * 4 + i;
            const int r = q * 8 + rsub;
            *(uint4*)&As[r * 72 + csub] = ra[i];
            *(uint4*)&Bs[r * 72 + csub] = rb[i];
        }
        __syncthreads();
#pragma unroll
        for (int s = 0; s < 2; s++) {
            bf16x8 af[4], bfr[4];
#pragma unroll
            for (int i = 0; i < 4; i++)
                af[i] = *(const bf16x8*)&As[(wm * 64 + i * 16 + lr) * 72 + s * 32 + lk * 8];
#pragma unroll
            for (int j = 0; j < 4; j++)
                bfr[j] = *(const bf16x8*)&Bs[(wn * 64 + j * 16 + lr) * 72 + s * 32 + lk * 8];
#pragma unroll
            for (int i = 0; i < 4; i++)
#pragma unroll
                for (int j = 0; j < 4; j++)
                    acc[i][j] = __builtin_amdgcn_mfma_f32_16x16x32_bf16(af[i], bfr[j], acc[i][j], 0, 0, 0);
        }
    }

    const int rowb = m0 + wm * 64, colb = n0 + wn * 64;
#pragma unroll
    for (int i = 0; i < 4; i++) {
#pragma unroll
        for (int j = 0; j < 4; j++) {
            const int col = colb + j * 16 + lr;
#pragma unroll
            for (int r = 0; r < 4; r++) {
                const int row = rowb + i * 16 + lk * 4 + r;
                float v = acc[i][j][r];
                if (EPI == EPI_PARTIAL) {
                    Cf[(size_t)blockIdx.z * ((size_t)M * N) + (size_t)row * N + col] = v;
                } else {
                    if (bias) v += bias[col];
                    if (EPI == EPI_BF16_RELU || EPI == EPI_F32_RELU) v = fmaxf(v, 0.f);
                    else if (EPI == EPI_F32_SP)  v = softplusf(v);
                    else if (EPI == EPI_F32_SIG) v = 1.f / (1.f + __expf(-v));
                    if (EPI == EPI_BF16_RELU || EPI == EPI_BF16_NONE) Cb[(size_t)row * N + col] = f2b(v);
                    else Cf[(size_t)row * N + col] = v;
                }
            }
        }
    }
}

// ---------- workspace layout (bytes) ----------
static constexpr size_t oPHIXWT  = 0;                      // [1024][512]
static constexpr size_t oWCATT   = 1048576;                // [2048][2048]
static constexpr size_t oEMW2T   = 9437184;                // [128][1024]
static constexpr size_t oESW2T   = 9699328;
static constexpr size_t oWIHPHIT = 9961472;                // [3072][1024]
static constexpr size_t oWIHZT   = 16252928;               // [3072][128]
static constexpr size_t oPMW1T   = 17039360;
static constexpr size_t oPMW2T   = 19136512;
static constexpr size_t oPSW1T   = 19398656;
static constexpr size_t oPSW2T   = 21495808;
static constexpr size_t oDMW1T   = 21757952;               // [1024][1152]
static constexpr size_t oDMW2T   = 24117248;               // [512][1024]
static constexpr size_t oHS      = 25165824;               // [T+1][B][H] bf16
static constexpr size_t oZBF     = 159907840;              // [T][B][Z] bf16
static constexpr size_t oT12     = 176685056;              // [256][2048] bf16
static constexpr size_t oBAR     = 177733632;              // slots[256]
static constexpr size_t oKLDT    = 177737728;
static constexpr size_t oNLLT    = 177738752;
static constexpr size_t oPHI     = 177739776;              // [65536][1024] bf16 (U1 in phase C)
static constexpr size_t oGIP     = 311957504;              // [65536][3072] bf16 (XbfT / PM / PS overlay)
static constexpr size_t WS_NEED  = 714610688;

static constexpr size_t NZ = (size_t)256 * 256 * 128;
static constexpr size_t O_Z  = 3;
static constexpr size_t O_MU = 3 + NZ;
static constexpr size_t O_STD = 3 + 2 * NZ;
static constexpr size_t O_XM = 3 + 3 * NZ;

// ---------- fence-free grid barrier (relaxed flag array, all-threads poll) ----------
__device__ __forceinline__ void gbar(unsigned* slots, unsigned n) {
    asm volatile("s_waitcnt vmcnt(0)" ::: "memory");   // write-through stores drained to IC
    __syncthreads();
    if (threadIdx.x == 0)
        __hip_atomic_store(&slots[blockIdx.x], n, __ATOMIC_RELAXED, __HIP_MEMORY_SCOPE_AGENT);
    while (__hip_atomic_load(&slots[threadIdx.x], __ATOMIC_RELAXED, __HIP_MEMORY_SCOPE_AGENT) < n)
        __builtin_amdgcn_s_sleep(4);
    __syncthreads();
}

// ---------- persistent sequential-phase kernel ----------
__global__ __launch_bounds__(256, 1)
void vrnn_seq(const float* __restrict__ eps,
              const float* __restrict__ em_b1, const float* __restrict__ es_b1,
              const float* __restrict__ em_b2, const float* __restrict__ es_b2,
              const float* __restrict__ gbih, const float* __restrict__ gbhh,
              char* ws, float* out) {
    __shared__ __align__(16) u16 SA[32 * 72];
    __shared__ __align__(16) u16 SB[64 * 72];
    __shared__ float zsL[16 * 32];
    __shared__ __align__(16) u16 TH[16 * 136];

    const int bx = blockIdx.x, tid = threadIdx.x;
    const int wid = tid >> 6, lane = tid & 63;
    const int lr = lane & 15, lk = lane >> 4;
    const int wm = wid >> 1, wn = wid & 1;
    const int sr = tid >> 3, sc = (tid & 7) * 8;

    const u16* wcatT = (const u16*)(ws + oWCATT);
    const u16* emW2T = (const u16*)(ws + oEMW2T);
    const u16* esW2T = (const u16*)(ws + oESW2T);
    const u16* wihZT = (const u16*)(ws + oWIHZT);
    const u16* PHI   = (const u16*)(ws + oPHI);
    const u16* GIP   = (const u16*)(ws + oGIP);
    u16* HS   = (u16*)(ws + oHS);
    u16* ZBFg = (u16*)(ws + oZBF);
    u16* T12g = (u16*)(ws + oT12);
    unsigned* slots = (unsigned*)(ws + oBAR);

    float* outZ  = out + O_Z;
    float* outMu = out + O_MU;
    float* outSd = out + O_STD;

    unsigned nb = 0;
    const int mI = bx >> 5, nI = bx & 31;     // W1 tile coords (M=32, N=64)

#pragma unroll 1
    for (int t = 0; t < 256; t++) {
        // ======== window 1: T12 = [h_t | phi_t] @ wcat  (ALL 256 blocks, 32x64 tiles) ========
        {
            const u16* HSt  = HS  + (size_t)t * 262144 + (size_t)(mI * 32) * 1024;
            const u16* PHIt = PHI + (size_t)t * 262144 + (size_t)(mI * 32) * 1024;
            const u16* Bb   = wcatT + (size_t)(nI * 64) * 2048;

            // preload the whole h-half A-slab (coherent, one batched IC round trip)
            uint2 ah[16][2];
#pragma unroll
            for (int kh = 0; kh < 16; kh++) {
                ah[kh][0] = ld_cg8(HSt + (size_t)sr * 1024 + kh * 64 + sc);
                ah[kh][1] = ld_cg8(HSt + (size_t)sr * 1024 + kh * 64 + sc + 4);
            }
            // B ring (4-deep) + A-phi ring
            uint4 rb[4][2], rap[4];
#pragma unroll
            for (int i = 0; i < 4; i++) {
                rb[i][0] = *(const uint4*)(Bb + (size_t)sr * 2048 + i * 64 + sc);
                rb[i][1] = *(const uint4*)(Bb + (size_t)(32 + sr) * 2048 + i * 64 + sc);
            }
            f32x4 acc0 = {0.f, 0.f, 0.f, 0.f}, acc1 = {0.f, 0.f, 0.f, 0.f};

#define W1_STAGE_B(KT) { \
    *(uint4*)&SB[(sr) * 72 + sc]      = rb[(KT) & 3][0]; \
    *(uint4*)&SB[(32 + sr) * 72 + sc] = rb[(KT) & 3][1]; }
#define W1_PF_B(KT) { \
    rb[(KT) & 3][0] = *(const uint4*)(Bb + (size_t)sr * 2048 + (KT + 4) * 64 + sc); \
    rb[(KT) & 3][1] = *(const uint4*)(Bb + (size_t)(32 + sr) * 2048 + (KT + 4) * 64 + sc); }
#define W1_MFMA() { \
    _Pragma("unroll") \
    for (int s_ = 0; s_ < 2; s_++) { \
        bf16x8 af_ = *(const bf16x8*)&SA[(wm * 16 + lr) * 72 + s_ * 32 + lk * 8]; \
        bf16x8 b0_ = *(const bf16x8*)&SB[(wn * 32 + lr) * 72 + s_ * 32 + lk * 8]; \
        bf16x8 b1_ = *(const bf16x8*)&SB[(wn * 32 + 16 + lr) * 72 + s_ * 32 + lk * 8]; \
        acc0 = __builtin_amdgcn_mfma_f32_16x16x32_bf16(af_, b0_, acc0, 0, 0, 0); \
        acc1 = __builtin_amdgcn_mfma_f32_16x16x32_bf16(af_, b1_, acc1, 0, 0, 0); \
    } }

#pragma unroll
            for (int kt = 0; kt < 16; kt++) {        // h half: A from regs
                __syncthreads();
                *(uint2*)&SA[sr * 72 + sc]     = ah[kt][0];
                *(uint2*)&SA[sr * 72 + sc + 4] = ah[kt][1];
                W1_STAGE_B(kt);
                __syncthreads();
                W1_PF_B(kt);
                if (kt >= 12)
                    rap[kt & 3] = *(const uint4*)(PHIt + (size_t)sr * 1024 + (kt - 12) * 64 + sc);
                W1_MFMA();
            }
#pragma unroll
            for (int p = 0; p < 16; p++) {           // phi half: A ring-prefetched
                __syncthreads();
                *(uint4*)&SA[sr * 72 + sc] = rap[p & 3];
                W1_STAGE_B(16 + p);
                __syncthreads();
                if (p < 12) {
                    W1_PF_B(16 + p);
                    rap[p & 3] = *(const uint4*)(PHIt + (size_t)sr * 1024 + (p + 4) * 64 + sc);
                }
                W1_MFMA();
            }
#undef W1_STAGE_B
#undef W1_PF_B
#undef W1_MFMA
            // epilogue: bias+relu -> LDS repack -> one coherent 16B store per thread
            __syncthreads();
#pragma unroll
            for (int j = 0; j < 2; j++) {
                const int colg = nI * 64 + wn * 32 + j * 16 + lr;
                const float bb = (colg < 1024) ? em_b1[colg] : es_b1[colg - 1024];
                const f32x4 a = j ? acc1 : acc0;
#pragma unroll
                for (int r = 0; r < 4; r++)
                    SA[(wm * 16 + lk * 4 + r) * 72 + wn * 32 + j * 16 + lr] =
                        f2b(fmaxf(a[r] + bb, 0.f));
            }
            __syncthreads();
            {
                uint4 v = *(const uint4*)&SA[sr * 72 + sc];
                st_cg16(T12g + (size_t)(mI * 32 + sr) * 2048 + nI * 64 + sc, v);
            }
        }
        gbar(slots, ++nb);

        // ======== window 2: zm/zs -> z  (blocks 0..63: 16 rows x 32 z-cols) ========
        if (bx < 64) {
            const int rg = bx >> 2, cg = bx & 3, r0 = rg * 16;
            const int half = wid & 1, csel = wid >> 1;
            const int c0 = cg * 32 + csel * 16;
            const u16* W2T  = half ? esW2T : emW2T;
            const u16* Arow = T12g + (size_t)(r0 + lr) * 2048 + half * 1024;
            const u16* Brow = W2T + (size_t)(c0 + lr) * 1024;
            f32x4 a4 = {0.f, 0.f, 0.f, 0.f};
#pragma unroll
            for (int kc = 0; kc < 2; kc++) {
                uint2 a2[16][2];
#pragma unroll
                for (int ks = 0; ks < 16; ks++) {
                    a2[ks][0] = ld_cg8(Arow + kc * 512 + ks * 32 + lk * 8);
                    a2[ks][1] = ld_cg8(Arow + kc * 512 + ks * 32 + lk * 8 + 4);
                }
#pragma unroll
                for (int ks = 0; ks < 16; ks++) {
                    bf16x8 af = mk8(a2[ks][0], a2[ks][1]);
                    bf16x8 bf = *(const bf16x8*)(Brow + kc * 512 + ks * 32 + lk * 8);
                    a4 = __builtin_amdgcn_mfma_f32_16x16x32_bf16(af, bf, a4, 0, 0, 0);
                }
            }
            const int colz = c0 + lr;
            if (half) {
#pragma unroll
                for (int r = 0; r < 4; r++)
                    zsL[(lk * 4 + r) * 32 + (csel * 16 + lr)] = softplusf(a4[r] + es_b2[colz]);
            }
            __syncthreads();
            if (!half) {
#pragma unroll
                for (int r = 0; r < 4; r++) {
                    const int row = lk * 4 + r;
                    const float zm = fmaxf(a4[r] + em_b2[colz], 0.f);
                    const float zs = zsL[row * 32 + (csel * 16 + lr)];
                    const size_t o = (size_t)t * 32768 + (size_t)(r0 + row) * 128 + colz;
                    const float z = zm + zs * eps[o];
                    outMu[o] = zm; outSd[o] = zs; outZ[o] = z;
                    st_cg2(ZBFg + o, (unsigned)f2b(z));
                }
            }
        }
        gbar(slots, ++nb);

        // ======== window 3: GRU -> h_{t+1}  (blocks 0..127: 16 rows x 128 h-cols) ========
        if (bx < 128) {
            const int rg = bx >> 3, cg = bx & 7, r0 = rg * 16;
            // coherent z fragments (one batch)
            uint2 z2[4][2];
            const u16* zrow = ZBFg + (size_t)t * 32768 + (size_t)(r0 + lr) * 128;
#pragma unroll
            for (int ks = 0; ks < 4; ks++) {
                z2[ks][0] = ld_cg8(zrow + ks * 32 + lk * 8);
                z2[ks][1] = ld_cg8(zrow + ks * 32 + lk * 8 + 4);
            }
            // prefetch all GIP gate values (normal cached loads, batched early)
            const u16* gipt = GIP + (size_t)t * 786432;
            u16 gR[2][4], gU[2][4], gN[2][4];
#pragma unroll
            for (int jj = 0; jj < 2; jj++) {
                const int col = (cg * 8 + wid * 2 + jj) * 16 + lr;
#pragma unroll
                for (int r = 0; r < 4; r++) {
                    const u16* gp = gipt + (size_t)(r0 + lk * 4 + r) * 3072;
                    gR[jj][r] = gp[col];
                    gU[jj][r] = gp[1024 + col];
                    gN[jj][r] = gp[2048 + col];
                }
            }
            bf16x8 zf[4];
#pragma unroll
            for (int ks = 0; ks < 4; ks++) zf[ks] = mk8(z2[ks][0], z2[ks][1]);

            u16* HSn = HS + (size_t)(t + 1) * 262144;
#pragma unroll
            for (int jj = 0; jj < 2; jj++) {
                const int jt = cg * 8 + wid * 2 + jj;
                const int col = jt * 16 + lr;
                f32x4 aR = {0.f,0.f,0.f,0.f}, aU = {0.f,0.f,0.f,0.f}, aN = {0.f,0.f,0.f,0.f};
#pragma unroll
                for (int ks = 0; ks < 4; ks++) {
                    const int ko = ks * 32 + lk * 8;
                    bf16x8 bR = *(const bf16x8*)(wihZT + (size_t)(       col) * 128 + ko);
                    bf16x8 bU = *(const bf16x8*)(wihZT + (size_t)(1024 + col) * 128 + ko);
                    bf16x8 bN = *(const bf16x8*)(wihZT + (size_t)(2048 + col) * 128 + ko);
                    aR = __builtin_amdgcn_mfma_f32_16x16x32_bf16(zf[ks], bR, aR, 0, 0, 0);
                    aU = __builtin_amdgcn_mfma_f32_16x16x32_bf16(zf[ks], bU, aU, 0, 0, 0);
                    aN = __builtin_amdgcn_mfma_f32_16x16x32_bf16(zf[ks], bN, aN, 0, 0, 0);
                }
                const float bihR = gbih[col],        bhR = gbhh[col];
                const float bihU = gbih[1024 + col], bhU = gbhh[1024 + col];
                const float bihN = gbih[2048 + col], bhN = gbhh[2048 + col];
#pragma unroll
                for (int r = 0; r < 4; r++) {
                    const float gr = aR[r] + b2f(gR[jj][r]) + bihR + bhR;
                    const float gu = aU[r] + b2f(gU[jj][r]) + bihU + bhU;
                    float gn       = aN[r] + b2f(gN[jj][r]) + bihN;
                    const float rr_ = 1.f / (1.f + __expf(-gr));
                    const float uu  = 1.f / (1.f + __expf(-gu));
                    gn += rr_ * bhN;
                    const float e2 = __expf(-2.f * fabsf(gn));
                    float th = (1.f - e2) / (1.f + e2);
                    th = (gn < 0.f) ? -th : th;
                    TH[(lk * 4 + r) * 136 + (wid * 2 + jj) * 16 + lr] = f2b((1.f - uu) * th);
                }
            }
            __syncthreads();
            {
                uint4 v = *(const uint4*)&TH[(tid >> 4) * 136 + (tid & 15) * 8];
                st_cg16(HSn + (size_t)(r0 + (tid >> 4)) * 1024 + cg * 128 + (tid & 15) * 8, v);
            }
        }
        gbar(slots, ++nb);
    }
}

// ---------- loss ----------
__global__ __launch_bounds__(256)
void loss_per_t(const float* __restrict__ x,
                const float* __restrict__ xm,
                const float* __restrict__ zm, const float* __restrict__ zs,
                const float* __restrict__ pm, const float* __restrict__ ps,
                float* __restrict__ kldT, float* __restrict__ nllT) {
    const int t = blockIdx.x, bb = threadIdx.x;
    float kld = 0.f, nll = 0.f;
    const size_t ozb = ((size_t)t * 256 + bb) * 128;
    for (int zz = 0; zz < 128; zz++) {
        const float qs = zs[ozb + zz], qm = zm[ozb + zz];
        const float pmv = pm[ozb + zz], psv = ps[ozb + zz];
        const float d = qm - pmv;
        kld += logf(psv + EPSC) - logf(qs + EPSC)
             + (qs * qs + d * d) / (2.f * psv * psv + EPSC) - 0.5f;
    }
    const size_t oxb = ((size_t)t * 256 + bb) * 512;
    const size_t oxi = ((size_t)bb * 256 + t) * 512;
    for (int dd = 0; dd < 512; dd++) {
        const float xv = x[oxi + dd];
        float m = xm[oxb + dd];
        m = fminf(fmaxf(m, 1e-6f), 1.f - 1e-6f);
        nll -= xv * logf(m) + (1.f - xv) * log1pf(-m);
    }
    __shared__ float sk[256], sn[256];
    sk[bb] = kld; sn[bb] = nll;
    __syncthreads();
    for (int s = 128; s > 0; s >>= 1) {
        if (bb < s) { sk[bb] += sk[bb + s]; sn[bb] += sn[bb + s]; }
        __syncthreads();
    }
    if (bb == 0) { kldT[t] = sk[0] / 256.f; nllT[t] = sn[0] / 256.f; }
}

__global__ __launch_bounds__(256)
void loss_final(const float* __restrict__ kldT, const float* __restrict__ nllT,
                float* __restrict__ out) {
    const int tid = threadIdx.x;
    __shared__ float s[256];
    s[tid] = kldT[tid] + nllT[tid];
    __syncthreads();
    for (int st = 128; st > 0; st >>= 1) {
        if (tid < st) s[tid] += s[tid + st];
        __syncthreads();
    }
    if (tid == 0) { out[0] = s[0]; out[1] = kldT[255]; out[2] = nllT[255]; }
}

extern "C" void kernel_launch(void* const* d_in, const int* in_sizes, int n_in,
                              void* d_out, int out_size, void* d_ws, size_t ws_size,
                              hipStream_t stream) {
    const float* x      = (const float*)d_in[0];
    const float* eps    = (const float*)d_in[1];
    const float* h0     = (const float*)d_in[2];
    const float* phix_w = (const float*)d_in[3];
    const float* phix_b = (const float*)d_in[4];
    const float* pm_w1  = (const float*)d_in[5];
    const float* pm_b1  = (const float*)d_in[6];
    const float* pm_w2  = (const float*)d_in[7];
    const float* pm_b2  = (const float*)d_in[8];
    const float* ps_w1  = (const float*)d_in[9];
    const float* ps_b1  = (const float*)d_in[10];
    const float* ps_w2  = (const float*)d_in[11];
    const float* ps_b2  = (const float*)d_in[12];
    const float* em_w1  = (const float*)d_in[13];
    const float* em_b1  = (const float*)d_in[14];
    const float* em_w2  = (const float*)d_in[15];
    const float* em_b2  = (const float*)d_in[16];
    const float* es_w1  = (const float*)d_in[17];
    const float* es_b1  = (const float*)d_in[18];
    const float* es_w2  = (const float*)d_in[19];
    const float* es_b2  = (const float*)d_in[20];
    const float* dm_w1  = (const float*)d_in[21];
    const float* dm_b1  = (const float*)d_in[22];
    const float* dm_w2  = (const float*)d_in[23];
    const float* dm_b2  = (const float*)d_in[24];
    const float* gwih   = (const float*)d_in[25];
    const float* gbih   = (const float*)d_in[26];
    const float* gbhh   = (const float*)d_in[27];
    float* out = (float*)d_out;

    if (ws_size < WS_NEED) return;
    char* w = (char*)d_ws;
    u16* phixWt  = (u16*)(w + oPHIXWT);
    u16* wcatT   = (u16*)(w + oWCATT);
    u16* emW2T   = (u16*)(w + oEMW2T);
    u16* esW2T   = (u16*)(w + oESW2T);
    u16* wihPhiT = (u16*)(w + oWIHPHIT);
    u16* wihZT   = (u16*)(w + oWIHZT);
    u16* pmW1T   = (u16*)(w + oPMW1T);
    u16* pmW2T   = (u16*)(w + oPMW2T);
    u16* psW1T   = (u16*)(w + oPSW1T);
    u16* psW2T   = (u16*)(w + oPSW2T);
    u16* dmW1T   = (u16*)(w + oDMW1T);
    u16* dmW2T   = (u16*)(w + oDMW2T);
    u16* HS      = (u16*)(w + oHS);
    u16* ZBF     = (u16*)(w + oZBF);
    u16* PHI     = (u16*)(w + oPHI);
    u16* GIP     = (u16*)(w + oGIP);
    u16* XbfT    = (u16*)(w + oGIP);                 // dead after phi GEMM
    float* PMbuf = (float*)(w + oGIP);               // phase C only (GIP dead)
    float* PSbuf = (float*)(w + oGIP + 33554432);
    unsigned* bar = (unsigned*)(w + oBAR);
    float* kldT  = (float*)(w + oKLDT);
    float* nllT  = (float*)(w + oNLLT);

    // ---- phase A: conversions / weight transposes / big precompute GEMMs ----
    conv_x4<<<32768, 256, 0, stream>>>(XbfT, x);
    conv_f32_bf16<<<1024, 256, 0, stream>>>(HS, h0, 262144);
    tr_conv<<<2048, 256, 0, stream>>>(phixWt, phix_w, 512, 1024, 1024);
    tr_conv<<<8192, 256, 0, stream>>>(wcatT, em_w1, 2048, 1024, 1024);
    tr_conv<<<8192, 256, 0, stream>>>(wcatT + (size_t)1024 * 2048, es_w1, 2048, 1024, 1024);
    tr_conv<<<512, 256, 0, stream>>>(emW2T, em_w2, 1024, 128, 128);
    tr_conv<<<512, 256, 0, stream>>>(esW2T, es_w2, 1024, 128, 128);
    tr_conv<<<12288, 256, 0, stream>>>(wihPhiT, gwih, 1024, 3072, 3072);
    tr_conv<<<1536, 256, 0, stream>>>(wihZT, gwih + (size_t)1024 * 3072, 128, 3072, 3072);
    tr_conv<<<4096, 256, 0, stream>>>(pmW1T, pm_w1, 1024, 1024, 1024);
    tr_conv<<<512, 256, 0, stream>>>(pmW2T, pm_w2, 1024, 128, 128);
    tr_conv<<<4096, 256, 0, stream>>>(psW1T, ps_w1, 1024, 1024, 1024);
    tr_conv<<<512, 256, 0, stream>>>(psW2T, ps_w2, 1024, 128, 128);
    tr_conv<<<4608, 256, 0, stream>>>(dmW1T, dm_w1, 1152, 1024, 1024);
    tr_conv<<<2048, 256, 0, stream>>>(dmW2T, dm_w2, 1024, 512, 512);

    // PHI = relu(x_t @ phix_w + b)  [65536, 1024]  (reads XbfT = GIP region start)
    gemm128<EPI_BF16_RELU><<<dim3(8, 512, 1), 256, 0, stream>>>(
        XbfT, nullptr, 512, 0, 512, phixWt, 512, phix_b, PHI, nullptr, 65536, 1024, 512, 512);
    // GIP = phi @ gru_wih[:H]  [65536, 3072]  (overwrites XbfT region)
    gemm128<EPI_BF16_NONE><<<dim3(24, 512, 1), 256, 0, stream>>>(
        PHI, nullptr, 1024, 0, 1024, wihPhiT, 1024, nullptr, GIP, nullptr, 65536, 3072, 1024, 1024);

    // ---- phase B: persistent sequential kernel ----
    init_ctr<<<1, 512, 0, stream>>>(bar);
    vrnn_seq<<<256, 256, 0, stream>>>(eps, em_b1, es_b1, em_b2, es_b2, gbih, gbhh,
                                      (char*)d_ws, out);

    // ---- phase C: deferred prior / decoder / loss ----
    gemm128<EPI_BF16_RELU><<<dim3(8, 512, 1), 256, 0, stream>>>(
        HS, nullptr, 1024, 0, 1024, pmW1T, 1024, pm_b1, PHI, nullptr, 65536, 1024, 1024, 1024);
    gemm128<EPI_F32_RELU><<<dim3(1, 512, 1), 256, 0, stream>>>(
        PHI, nullptr, 1024, 0, 1024, pmW2T, 1024, pm_b2, nullptr, PMbuf, 65536, 128, 1024, 1024);
    gemm128<EPI_BF16_RELU><<<dim3(8, 512, 1), 256, 0, stream>>>(
        HS, nullptr, 1024, 0, 1024, psW1T, 1024, ps_b1, PHI, nullptr, 65536, 1024, 1024, 1024);
    gemm128<EPI_F32_SP><<<dim3(1, 512, 1), 256, 0, stream>>>(
        PHI, nullptr, 1024, 0, 1024, psW2T, 1024, ps_b2, nullptr, PSbuf, 65536, 128, 1024, 1024);
    gemm128<EPI_BF16_RELU><<<dim3(8, 512, 1), 256, 0, stream>>>(
        HS, ZBF, 1024, 128, 1024, dmW1T, 1152, dm_b1, PHI, nullptr, 65536, 1024, 1152, 1152);
    gemm128<EPI_F32_SIG><<<dim3(4, 512, 1), 256, 0, stream>>>(
        PHI, nullptr, 1024, 0, 1024, dmW2T, 1024, dm_b2, nullptr, out + O_XM, 65536, 512, 1024, 1024);

    loss_per_t<<<256, 256, 0, stream>>>(x, out + O_XM, out + O_MU, out + O_STD,
                                        PMbuf, PSbuf, kldT, nllT);
    loss_final<<<1, 256, 0, stream>>>(kldT, nllT, out);
}

// Round 7
// 24308.942 us; speedup vs baseline: 11.9445x; 1.1264x over previous
//
#include <hip/hip_runtime.h>

typedef unsigned short u16;
typedef __bf16 bf16x8 __attribute__((ext_vector_type(8)));
typedef float f32x4 __attribute__((ext_vector_type(4)));
typedef unsigned uint32x4 __attribute__((ext_vector_type(4)));

#define EPSC 1e-6f

// ---------- helpers ----------
__device__ __forceinline__ float b2f(u16 x) { return __uint_as_float(((unsigned)x) << 16); }
__device__ __forceinline__ u16 f2b(float f) {
    unsigned u = __float_as_uint(f);
    unsigned r = (u + 0x7fffu + ((u >> 16) & 1u)) >> 16;
    return (u16)r;
}
__device__ __forceinline__ float softplusf(float x) {
    return fmaxf(x, 0.f) + log1pf(__expf(-fabsf(x)));
}

// ---- coherent (cross-XCD) plain-load/store primitives: per-instruction sc0|sc1
// cache policy (bypass L1/L2 to the IC coherence point). NOT atomics -> no RMW,
// fully pipelined. ext_vector operand types keep clang's "v" constraints happy.
__device__ __forceinline__ void ld_cv16_issue(uint32x4& d, const void* p) {
    asm volatile("global_load_dwordx4 %0, %1, off sc0 sc1"
                 : "=v"(d) : "v"((unsigned long long)p) : "memory");
}
__device__ __forceinline__ unsigned ld_cv4(const void* p) {
    unsigned d;
    asm volatile("global_load_dword %0, %1, off sc0 sc1\n\ts_waitcnt vmcnt(0)"
                 : "=v"(d) : "v"((unsigned long long)p) : "memory");
    return d;
}
__device__ __forceinline__ void wait_vm0() {
    asm volatile("s_waitcnt vmcnt(0)" ::: "memory");
    __builtin_amdgcn_sched_barrier(0);
}
__device__ __forceinline__ void st_cv16(void* p, uint32x4 v) {
    asm volatile("global_store_dwordx4 %0, %1, off sc0 sc1"
                 :: "v"((unsigned long long)p), "v"(v) : "memory");
}
__device__ __forceinline__ void st_cv4(void* p, unsigned v) {
    asm volatile("global_store_dword %0, %1, off sc0 sc1"
                 :: "v"((unsigned long long)p), "v"(v) : "memory");
}
__device__ __forceinline__ void st_cv2(void* p, unsigned v) {
    asm volatile("global_store_short %0, %1, off sc0 sc1"
                 :: "v"((unsigned long long)p), "v"(v) : "memory");
}
__device__ __forceinline__ bf16x8 cast8(uint32x4 v) {
    return __builtin_bit_cast(bf16x8, v);
}

// ---------- conversion / transpose kernels ----------
__global__ void conv_x4(u16* __restrict__ dst, const float* __restrict__ x) {
    size_t i4 = (size_t)blockIdx.x * 256 + threadIdx.x;
    size_t o = i4 * 4;
    int d = (int)(o & 511);
    int b = (int)((o >> 9) & 255);
    int t = (int)(o >> 17);
    float4 v = *(const float4*)(x + ((size_t)b * 256 + t) * 512 + d);
    unsigned p0 = (unsigned)f2b(v.x) | ((unsigned)f2b(v.y) << 16);
    unsigned p1 = (unsigned)f2b(v.z) | ((unsigned)f2b(v.w) << 16);
    *(uint2*)(dst + o) = make_uint2(p0, p1);
}

__global__ void conv_f32_bf16(u16* __restrict__ dst, const float* __restrict__ src, int n) {
    int i = blockIdx.x * 256 + threadIdx.x;
    if (i < n) dst[i] = f2b(src[i]);
}

__global__ void tr_conv(u16* __restrict__ dst, const float* __restrict__ src,
                        int R, int C, int ld) {
    int idx = blockIdx.x * 256 + threadIdx.x;
    if (idx >= R * C) return;
    int c = idx / R, r = idx % R;
    dst[idx] = f2b(src[(size_t)r * ld + c]);
}

__global__ void init_ctr(unsigned* bar) {
#pragma unroll
    for (int i = 0; i < 4; i++) bar[threadIdx.x + i * 256] = 0u;
}

// ---------- generic 128x128 bf16 MFMA GEMM (phase A/C) ----------
enum { EPI_PARTIAL = 0, EPI_BF16_RELU = 1, EPI_BF16_NONE = 2,
       EPI_F32_RELU = 3, EPI_F32_SP = 4, EPI_F32_SIG = 5 };

template <int EPI>
__global__ __launch_bounds__(256)
void gemm128(const u16* __restrict__ A0, const u16* __restrict__ A1,
             int lda0, int lda1, int kSplit,
             const u16* __restrict__ Wt, int ldw,
             const float* __restrict__ bias,
             u16* __restrict__ Cb, float* __restrict__ Cf,
             int M, int N, int K, int kChunk) {
    __shared__ __align__(16) u16 As[128 * 72];
    __shared__ __align__(16) u16 Bs[128 * 72];
    const int tid = threadIdx.x;
    const int wid = tid >> 6, lane = tid & 63;
    const int wm = wid >> 1, wn = wid & 1;
    const int lr = lane & 15, lk = lane >> 4;
    const int m0 = blockIdx.y * 128, n0 = blockIdx.x * 128;
    const int kBeg = blockIdx.z * kChunk;
    const int rsub = lane >> 3;
    const int csub = (lane & 7) * 8;

    f32x4 acc[4][4];
#pragma unroll
    for (int i = 0; i < 4; i++)
#pragma unroll
        for (int j = 0; j < 4; j++) { f32x4 z = {0.f, 0.f, 0.f, 0.f}; acc[i][j] = z; }

    for (int kt = 0; kt < kChunk; kt += 64) {
        const int k0 = kBeg + kt;
        const u16* Ap; int kk, lda;
        if (k0 < kSplit) { Ap = A0; kk = k0; lda = lda0; }
        else             { Ap = A1; kk = k0 - kSplit; lda = lda1; }
        uint4 ra[4], rb[4];
#pragma unroll
        for (int i = 0; i < 4; i++) {
            const int q = wid * 4 + i;
            const int r = q * 8 + rsub;
            ra[i] = *(const uint4*)(Ap + (size_t)(m0 + r) * lda + kk + csub);
            rb[i] = *(const uint4*)(Wt + (size_t)(n0 + r) * ldw + k0 + csub);
        }
        __syncthreads();
#pragma unroll
        for (int i = 0; i < 4; i++) {
            const int q = wid * 4 + i;
            const int r = q * 8 + rsub;
            *(uint4*)&As[r * 72 + csub] = ra[i];
            *(uint4*)&Bs[r * 72 + csub] = rb[i];
        }
        __syncthreads();
#pragma unroll
        for (int s = 0; s < 2; s++) {
            bf16x8 af[4], bfr[4];
#pragma unroll
            for (int i = 0; i < 4; i++)
                af[i] = *(const bf16x8*)&As[(wm * 64 + i * 16 + lr) * 72 + s * 32 + lk * 8];
#pragma unroll
            for (int j = 0; j < 4; j++)
                bfr[j] = *(const bf16x8*)&Bs[(wn * 64 + j * 16 + lr) * 72 + s * 32 + lk * 8];
#pragma unroll
            for (int i = 0; i < 4; i++)
#pragma unroll
                for (int j = 0; j < 4; j++)
                    acc[i][j] = __builtin_amdgcn_mfma_f32_16x16x32_bf16(af[i], bfr[j], acc[i][j], 0, 0, 0);
        }
    }

    const int rowb = m0 + wm * 64, colb = n0 + wn * 64;
#pragma unroll
    for (int i = 0; i < 4; i++) {
#pragma unroll
        for (int j = 0; j < 4; j++) {
            const int col = colb + j * 16 + lr;
#pragma unroll
            for (int r = 0; r < 4; r++) {
                const int row = rowb + i * 16 + lk * 4 + r;
                float v = acc[i][j][r];
                if (EPI == EPI_PARTIAL) {
                    Cf[(size_t)blockIdx.z * ((size_t)M * N) + (size_t)row * N + col] = v;
                } else {
                    if (bias) v += bias[col];
                    if (EPI == EPI_BF16_RELU || EPI == EPI_F32_RELU) v = fmaxf(v, 0.f);
                    else if (EPI == EPI_F32_SP)  v = softplusf(v);
                    else if (EPI == EPI_F32_SIG) v = 1.f / (1.f + __expf(-v));
                    if (EPI == EPI_BF16_RELU || EPI == EPI_BF16_NONE) Cb[(size_t)row * N + col] = f2b(v);
                    else Cf[(size_t)row * N + col] = v;
                }
            }
        }
    }
}

// ---------- workspace layout (bytes) ----------
static constexpr size_t oPHIXWT  = 0;                      // [1024][512]
static constexpr size_t oWCATT   = 1048576;                // [2048][2048]
static constexpr size_t oEMW2T   = 9437184;                // [128][1024]
static constexpr size_t oESW2T   = 9699328;
static constexpr size_t oWIHPHIT = 9961472;                // [3072][1024]
static constexpr size_t oWIHZT   = 16252928;               // [3072][128]
static constexpr size_t oPMW1T   = 17039360;
static constexpr size_t oPMW2T   = 19136512;
static constexpr size_t oPSW1T   = 19398656;
static constexpr size_t oPSW2T   = 21495808;
static constexpr size_t oDMW1T   = 21757952;               // [1024][1152]
static constexpr size_t oDMW2T   = 24117248;               // [512][1024]
static constexpr size_t oHS      = 25165824;               // [T+1][B][H] bf16
static constexpr size_t oZBF     = 159907840;              // [T][B][Z] bf16
static constexpr size_t oT12     = 176685056;              // [256][2048] bf16
static constexpr size_t oBAR     = 177733632;              // 4 KB: slots (8B stride) + masters (64B stride)
static constexpr size_t oKLDT    = 177737728;
static constexpr size_t oNLLT    = 177738752;
static constexpr size_t oPHI     = 177739776;              // [65536][1024] bf16 (U1 in phase C)
static constexpr size_t oGIP     = 311957504;              // [65536][3072] bf16 (XbfT / PM / PS overlay)
static constexpr size_t WS_NEED  = 714610688;

static constexpr size_t NZ = (size_t)256 * 256 * 128;
static constexpr size_t O_Z  = 3;
static constexpr size_t O_MU = 3 + NZ;
static constexpr size_t O_STD = 3 + 2 * NZ;
static constexpr size_t O_XM = 3 + 3 * NZ;

// ---------- fence-free, atomic-free grid barrier (1 polling lane per block) ----------
__device__ __forceinline__ void gbar(unsigned* bar, unsigned n) {
    asm volatile("s_waitcnt vmcnt(0)" ::: "memory");   // sc1 stores drained to IC
    __syncthreads();
    const int bx = blockIdx.x, tid = threadIdx.x;
    if (bx == 0) {
        if (tid > 0)
            while (ld_cv4(bar + tid * 2) < n) __builtin_amdgcn_s_sleep(2);
        __syncthreads();
        if (tid < 8) st_cv4(bar + 512 + tid * 16, n);
        __syncthreads();
    } else {
        if (tid == 0) {
            st_cv4(bar + bx * 2, n);
            while (ld_cv4(bar + 512 + (bx & 7) * 16) < n) __builtin_amdgcn_s_sleep(2);
        }
        __syncthreads();
    }
}

// ---------- persistent sequential-phase kernel ----------
__global__ __launch_bounds__(256, 1)
void vrnn_seq(const float* __restrict__ eps,
              const float* __restrict__ em_b1, const float* __restrict__ es_b1,
              const float* __restrict__ em_b2, const float* __restrict__ es_b2,
              const float* __restrict__ gbih, const float* __restrict__ gbhh,
              char* ws, float* out) {
    __shared__ __align__(16) u16 SA[32 * 72];
    __shared__ __align__(16) u16 SB[64 * 72];
    __shared__ float zsL[16 * 32];
    __shared__ __align__(16) u16 TH[16 * 136];

    const int bx = blockIdx.x, tid = threadIdx.x;
    const int wid = tid >> 6, lane = tid & 63;
    const int lr = lane & 15, lk = lane >> 4;
    const int wm = wid >> 1, wn = wid & 1;
    const int sr = tid >> 3, sc = (tid & 7) * 8;

    const u16* wcatT = (const u16*)(ws + oWCATT);
    const u16* emW2T = (const u16*)(ws + oEMW2T);
    const u16* esW2T = (const u16*)(ws + oESW2T);
    const u16* wihZT = (const u16*)(ws + oWIHZT);
    const u16* PHI   = (const u16*)(ws + oPHI);
    const u16* GIP   = (const u16*)(ws + oGIP);
    u16* HS   = (u16*)(ws + oHS);
    u16* ZBFg = (u16*)(ws + oZBF);
    u16* T12g = (u16*)(ws + oT12);
    unsigned* bar = (unsigned*)(ws + oBAR);

    float* outZ  = out + O_Z;
    float* outMu = out + O_MU;
    float* outSd = out + O_STD;

    unsigned nb = 0;
    // XCD-aware W1 tile map: per XCD -> 4 mI slabs (256 KB A) + 8 nI slabs (2 MB wcat, L2-resident)
    const int xq = bx & 7, jq = bx >> 3;
    const int mI = (xq & 1) * 4 + (jq & 3);
    const int nI = (xq >> 1) + ((jq >> 2) * 4);

#pragma unroll 1
    for (int t = 0; t < 256; t++) {
        // ======== window 1: T12 = [h_t | phi_t] @ wcat  (ALL 256 blocks, 32x64 tiles) ========
        {
            const u16* HSt  = HS  + (size_t)t * 262144 + (size_t)(mI * 32) * 1024;
            const u16* PHIt = PHI + (size_t)t * 262144 + (size_t)(mI * 32) * 1024;
            const u16* Bb   = wcatT + (size_t)(nI * 64) * 2048;

            // coherent h-slab preload: 16 batched asm loads, one wait
            uint32x4 ahx[16];
#pragma unroll
            for (int kh = 0; kh < 16; kh++)
                ld_cv16_issue(ahx[kh], HSt + (size_t)sr * 1024 + kh * 64 + sc);
            wait_vm0();

            // B ring (4-deep, normal cached loads) + A-phi ring
            uint4 rb[4][2], rap[4];
#pragma unroll
            for (int i = 0; i < 4; i++) {
                rb[i][0] = *(const uint4*)(Bb + (size_t)sr * 2048 + i * 64 + sc);
                rb[i][1] = *(const uint4*)(Bb + (size_t)(32 + sr) * 2048 + i * 64 + sc);
            }
            f32x4 acc0 = {0.f, 0.f, 0.f, 0.f}, acc1 = {0.f, 0.f, 0.f, 0.f};

#define W1_STAGE_B(KT) { \
    *(uint4*)&SB[(sr) * 72 + sc]      = rb[(KT) & 3][0]; \
    *(uint4*)&SB[(32 + sr) * 72 + sc] = rb[(KT) & 3][1]; }
#define W1_PF_B(KT) { \
    rb[(KT) & 3][0] = *(const uint4*)(Bb + (size_t)sr * 2048 + (KT + 4) * 64 + sc); \
    rb[(KT) & 3][1] = *(const uint4*)(Bb + (size_t)(32 + sr) * 2048 + (KT + 4) * 64 + sc); }
#define W1_MFMA() { \
    _Pragma("unroll") \
    for (int s_ = 0; s_ < 2; s_++) { \
        bf16x8 af_ = *(const bf16x8*)&SA[(wm * 16 + lr) * 72 + s_ * 32 + lk * 8]; \
        bf16x8 b0_ = *(const bf16x8*)&SB[(wn * 32 + lr) * 72 + s_ * 32 + lk * 8]; \
        bf16x8 b1_ = *(const bf16x8*)&SB[(wn * 32 + 16 + lr) * 72 + s_ * 32 + lk * 8]; \
        acc0 = __builtin_amdgcn_mfma_f32_16x16x32_bf16(af_, b0_, acc0, 0, 0, 0); \
        acc1 = __builtin_amdgcn_mfma_f32_16x16x32_bf16(af_, b1_, acc1, 0, 0, 0); \
    } }

#pragma unroll
            for (int kt = 0; kt < 16; kt++) {        // h half: A from regs
                __syncthreads();
                *(uint32x4*)&SA[sr * 72 + sc] = ahx[kt];
                W1_STAGE_B(kt);
                __syncthreads();
                W1_PF_B(kt);
                if (kt >= 12)
                    rap[kt & 3] = *(const uint4*)(PHIt + (size_t)sr * 1024 + (kt - 12) * 64 + sc);
                W1_MFMA();
            }
#pragma unroll
            for (int p = 0; p < 16; p++) {           // phi half: A ring-prefetched
                __syncthreads();
                *(uint4*)&SA[sr * 72 + sc] = rap[p & 3];
                W1_STAGE_B(16 + p);
                __syncthreads();
                if (p < 12) {
                    W1_PF_B(16 + p);
                    rap[p & 3] = *(const uint4*)(PHIt + (size_t)sr * 1024 + (p + 4) * 64 + sc);
                }
                W1_MFMA();
            }
#undef W1_STAGE_B
#undef W1_PF_B
#undef W1_MFMA
            // epilogue: bias+relu -> LDS repack -> one coherent 16B asm store per thread
            __syncthreads();
#pragma unroll
            for (int j = 0; j < 2; j++) {
                const int colg = nI * 64 + wn * 32 + j * 16 + lr;
                const float bb = (colg < 1024) ? em_b1[colg] : es_b1[colg - 1024];
                const f32x4 a = j ? acc1 : acc0;
#pragma unroll
                for (int r = 0; r < 4; r++)
                    SA[(wm * 16 + lk * 4 + r) * 72 + wn * 32 + j * 16 + lr] =
                        f2b(fmaxf(a[r] + bb, 0.f));
            }
            __syncthreads();
            {
                uint32x4 v = *(const uint32x4*)&SA[sr * 72 + sc];
                st_cv16(T12g + (size_t)(mI * 32 + sr) * 2048 + nI * 64 + sc, v);
            }
        }
        gbar(bar, ++nb);

        // ======== window 2: zm/zs -> z  (blocks 0..63: 16 rows x 32 z-cols) ========
        if (bx < 64) {
            const int rg = bx >> 2, cg = bx & 3, r0 = rg * 16;
            const int half = wid & 1, csel = wid >> 1;
            const int c0 = cg * 32 + csel * 16;
            const u16* W2T  = half ? esW2T : emW2T;
            const u16* Arow = T12g + (size_t)(r0 + lr) * 2048 + half * 1024;
            const u16* Brow = W2T + (size_t)(c0 + lr) * 1024;
            f32x4 a4 = {0.f, 0.f, 0.f, 0.f};
#pragma unroll
            for (int kc = 0; kc < 2; kc++) {
                uint32x4 a2x[16];
#pragma unroll
                for (int ks = 0; ks < 16; ks++)
                    ld_cv16_issue(a2x[ks], Arow + kc * 512 + ks * 32 + lk * 8);
                wait_vm0();
#pragma unroll
                for (int ks = 0; ks < 16; ks++) {
                    bf16x8 bf = *(const bf16x8*)(Brow + kc * 512 + ks * 32 + lk * 8);
                    a4 = __builtin_amdgcn_mfma_f32_16x16x32_bf16(cast8(a2x[ks]), bf, a4, 0, 0, 0);
                }
            }
            const int colz = c0 + lr;
            if (half) {
#pragma unroll
                for (int r = 0; r < 4; r++)
                    zsL[(lk * 4 + r) * 32 + (csel * 16 + lr)] = softplusf(a4[r] + es_b2[colz]);
            }
            __syncthreads();
            if (!half) {
#pragma unroll
                for (int r = 0; r < 4; r++) {
                    const int row = lk * 4 + r;
                    const float zm = fmaxf(a4[r] + em_b2[colz], 0.f);
                    const float zs = zsL[row * 32 + (csel * 16 + lr)];
                    const size_t o = (size_t)t * 32768 + (size_t)(r0 + row) * 128 + colz;
                    const float z = zm + zs * eps[o];
                    outMu[o] = zm; outSd[o] = zs; outZ[o] = z;
                    st_cv2(ZBFg + o, (unsigned)f2b(z));
                }
            }
        }
        gbar(bar, ++nb);

        // ======== window 3: GRU -> h_{t+1}  (blocks 0..127: 16 rows x 128 h-cols) ========
        if (bx < 128) {
            const int rg = bx >> 3, cg = bx & 7, r0 = rg * 16;
            // coherent z fragments: 4 batched asm loads, one wait
            uint32x4 zx[4];
            const u16* zrow = ZBFg + (size_t)t * 32768 + (size_t)(r0 + lr) * 128;
#pragma unroll
            for (int ks = 0; ks < 4; ks++)
                ld_cv16_issue(zx[ks], zrow + ks * 32 + lk * 8);
            wait_vm0();
            // prefetch all GIP gate values (normal cached loads, batched early)
            const u16* gipt = GIP + (size_t)t * 786432;
            u16 gR[2][4], gU[2][4], gN[2][4];
#pragma unroll
            for (int jj = 0; jj < 2; jj++) {
                const int col = (cg * 8 + wid * 2 + jj) * 16 + lr;
#pragma unroll
                for (int r = 0; r < 4; r++) {
                    const u16* gp = gipt + (size_t)(r0 + lk * 4 + r) * 3072;
                    gR[jj][r] = gp[col];
                    gU[jj][r] = gp[1024 + col];
                    gN[jj][r] = gp[2048 + col];
                }
            }
            bf16x8 zf[4];
#pragma unroll
            for (int ks = 0; ks < 4; ks++) zf[ks] = cast8(zx[ks]);

            u16* HSn = HS + (size_t)(t + 1) * 262144;
#pragma unroll
            for (int jj = 0; jj < 2; jj++) {
                const int jt = cg * 8 + wid * 2 + jj;
                const int col = jt * 16 + lr;
                f32x4 aR = {0.f,0.f,0.f,0.f}, aU = {0.f,0.f,0.f,0.f}, aN = {0.f,0.f,0.f,0.f};
#pragma unroll
                for (int ks = 0; ks < 4; ks++) {
                    const int ko = ks * 32 + lk * 8;
                    bf16x8 bR = *(const bf16x8*)(wihZT + (size_t)(       col) * 128 + ko);
                    bf16x8 bU = *(const bf16x8*)(wihZT + (size_t)(1024 + col) * 128 + ko);
                    bf16x8 bN = *(const bf16x8*)(wihZT + (size_t)(2048 + col) * 128 + ko);
                    aR = __builtin_amdgcn_mfma_f32_16x16x32_bf16(zf[ks], bR, aR, 0, 0, 0);
                    aU = __builtin_amdgcn_mfma_f32_16x16x32_bf16(zf[ks], bU, aU, 0, 0, 0);
                    aN = __builtin_amdgcn_mfma_f32_16x16x32_bf16(zf[ks], bN, aN, 0, 0, 0);
                }
                const float bihR = gbih[col],        bhR = gbhh[col];
                const float bihU = gbih[1024 + col], bhU = gbhh[1024 + col];
                const float bihN = gbih[2048 + col], bhN = gbhh[2048 + col];
#pragma unroll
                for (int r = 0; r < 4; r++) {
                    const float gr = aR[r] + b2f(gR[jj][r]) + bihR + bhR;
                    const float gu = aU[r] + b2f(gU[jj][r]) + bihU + bhU;
                    float gn       = aN[r] + b2f(gN[jj][r]) + bihN;
                    const float rr_ = 1.f / (1.f + __expf(-gr));
                    const float uu  = 1.f / (1.f + __expf(-gu));
                    gn += rr_ * bhN;
                    const float e2 = __expf(-2.f * fabsf(gn));
                    float th = (1.f - e2) / (1.f + e2);
                    th = (gn < 0.f) ? -th : th;
                    TH[(lk * 4 + r) * 136 + (wid * 2 + jj) * 16 + lr] = f2b((1.f - uu) * th);
                }
            }
            __syncthreads();
            {
                uint32x4 v = *(const uint32x4*)&TH[(tid >> 4) * 136 + (tid & 15) * 8];
                st_cv16(HSn + (size_t)(r0 + (tid >> 4)) * 1024 + cg * 128 + (tid & 15) * 8, v);
            }
        }
        gbar(bar, ++nb);
    }
}

// ---------- loss ----------
__global__ __launch_bounds__(256)
void loss_per_t(const float* __restrict__ x,
                const float* __restrict__ xm,
                const float* __restrict__ zm, const float* __restrict__ zs,
                const float* __restrict__ pm, const float* __restrict__ ps,
                float* __restrict__ kldT, float* __restrict__ nllT) {
    const int t = blockIdx.x, bb = threadIdx.x;
    float kld = 0.f, nll = 0.f;
    const size_t ozb = ((size_t)t * 256 + bb) * 128;
    for (int zz = 0; zz < 128; zz++) {
        const float qs = zs[ozb + zz], qm = zm[ozb + zz];
        const float pmv = pm[ozb + zz], psv = ps[ozb + zz];
        const float d = qm - pmv;
        kld += logf(psv + EPSC) - logf(qs + EPSC)
             + (qs * qs + d * d) / (2.f * psv * psv + EPSC) - 0.5f;
    }
    const size_t oxb = ((size_t)t * 256 + bb) * 512;
    const size_t oxi = ((size_t)bb * 256 + t) * 512;
    for (int dd = 0; dd < 512; dd++) {
        const float xv = x[oxi + dd];
        float m = xm[oxb + dd];
        m = fminf(fmaxf(m, 1e-6f), 1.f - 1e-6f);
        nll -= xv * logf(m) + (1.f - xv) * log1pf(-m);
    }
    __shared__ float sk[256], sn[256];
    sk[bb] = kld; sn[bb] = nll;
    __syncthreads();
    for (int s = 128; s > 0; s >>= 1) {
        if (bb < s) { sk[bb] += sk[bb + s]; sn[bb] += sn[bb + s]; }
        __syncthreads();
    }
    if (bb == 0) { kldT[t] = sk[0] / 256.f; nllT[t] = sn[0] / 256.f; }
}

__global__ __launch_bounds__(256)
void loss_final(const float* __restrict__ kldT, const float* __restrict__ nllT,
                float* __restrict__ out) {
    const int tid = threadIdx.x;
    __shared__ float s[256];
    s[tid] = kldT[tid] + nllT[tid];
    __syncthreads();
    for (int st = 128; st > 0; st >>= 1) {
        if (tid < st) s[tid] += s[tid + st];
        __syncthreads();
    }
    if (tid == 0) { out[0] = s[0]; out[1] = kldT[255]; out[2] = nllT[255]; }
}

extern "C" void kernel_launch(void* const* d_in, const int* in_sizes, int n_in,
                              void* d_out, int out_size, void* d_ws, size_t ws_size,
                              hipStream_t stream) {
    const float* x      = (const float*)d_in[0];
    const float* eps    = (const float*)d_in[1];
    const float* h0     = (const float*)d_in[2];
    const float* phix_w = (const float*)d_in[3];
    const float* phix_b = (const float*)d_in[4];
    const float* pm_w1  = (const float*)d_in[5];
    const float* pm_b1  = (const float*)d_in[6];
    const float* pm_w2  = (const float*)d_in[7];
    const float* pm_b2  = (const float*)d_in[8];
    const float* ps_w1  = (const float*)d_in[9];
    const float* ps_b1  = (const float*)d_in[10];
    const float* ps_w2  = (const float*)d_in[11];
    const float* ps_b2  = (const float*)d_in[12];
    const float* em_w1  = (const float*)d_in[13];
    const float* em_b1  = (const float*)d_in[14];
    const float* em_w2  = (const float*)d_in[15];
    const float* em_b2  = (const float*)d_in[16];
    const float* es_w1  = (const float*)d_in[17];
    const float* es_b1  = (const float*)d_in[18];
    const float* es_w2  = (const float*)d_in[19];
    const float* es_b2  = (const float*)d_in[20];
    const float* dm_w1  = (const float*)d_in[21];
    const float* dm_b1  = (const float*)d_in[22];
    const float* dm_w2  = (const float*)d_in[23];
    const float* dm_b2  = (const float*)d_in[24];
    const float* gwih   = (const float*)d_in[25];
    const float* gbih   = (const float*)d_in[26];
    const float* gbhh   = (const float*)d_in[27];
    float* out = (float*)d_out;

    if (ws_size < WS_NEED) return;
    char* w = (char*)d_ws;
    u16* phixWt  = (u16*)(w + oPHIXWT);
    u16* wcatT   = (u16*)(w + oWCATT);
    u16* emW2T   = (u16*)(w + oEMW2T);
    u16* esW2T   = (u16*)(w + oESW2T);
    u16* wihPhiT = (u16*)(w + oWIHPHIT);
    u16* wihZT   = (u16*)(w + oWIHZT);
    u16* pmW1T   = (u16*)(w + oPMW1T);
    u16* pmW2T   = (u16*)(w + oPMW2T);
    u16* psW1T   = (u16*)(w + oPSW1T);
    u16* psW2T   = (u16*)(w + oPSW2T);
    u16* dmW1T   = (u16*)(w + oDMW1T);
    u16* dmW2T   = (u16*)(w + oDMW2T);
    u16* HS      = (u16*)(w + oHS);
    u16* ZBF     = (u16*)(w + oZBF);
    u16* PHI     = (u16*)(w + oPHI);
    u16* GIP     = (u16*)(w + oGIP);
    u16* XbfT    = (u16*)(w + oGIP);                 // dead after phi GEMM
    float* PMbuf = (float*)(w + oGIP);               // phase C only (GIP dead)
    float* PSbuf = (float*)(w + oGIP + 33554432);
    unsigned* bar = (unsigned*)(w + oBAR);
    float* kldT  = (float*)(w + oKLDT);
    float* nllT  = (float*)(w + oNLLT);

    // ---- phase A: conversions / weight transposes / big precompute GEMMs ----
    conv_x4<<<32768, 256, 0, stream>>>(XbfT, x);
    conv_f32_bf16<<<1024, 256, 0, stream>>>(HS, h0, 262144);
    tr_conv<<<2048, 256, 0, stream>>>(phixWt, phix_w, 512, 1024, 1024);
    tr_conv<<<8192, 256, 0, stream>>>(wcatT, em_w1, 2048, 1024, 1024);
    tr_conv<<<8192, 256, 0, stream>>>(wcatT + (size_t)1024 * 2048, es_w1, 2048, 1024, 1024);
    tr_conv<<<512, 256, 0, stream>>>(emW2T, em_w2, 1024, 128, 128);
    tr_conv<<<512, 256, 0, stream>>>(esW2T, es_w2, 1024, 128, 128);
    tr_conv<<<12288, 256, 0, stream>>>(wihPhiT, gwih, 1024, 3072, 3072);
    tr_conv<<<1536, 256, 0, stream>>>(wihZT, gwih + (size_t)1024 * 3072, 128, 3072, 3072);
    tr_conv<<<4096, 256, 0, stream>>>(pmW1T, pm_w1, 1024, 1024, 1024);
    tr_conv<<<512, 256, 0, stream>>>(pmW2T, pm_w2, 1024, 128, 128);
    tr_conv<<<4096, 256, 0, stream>>>(psW1T, ps_w1, 1024, 1024, 1024);
    tr_conv<<<512, 256, 0, stream>>>(psW2T, ps_w2, 1024, 128, 128);
    tr_conv<<<4608, 256, 0, stream>>>(dmW1T, dm_w1, 1152, 1024, 1024);
    tr_conv<<<2048, 256, 0, stream>>>(dmW2T, dm_w2, 1024, 512, 512);

    // PHI = relu(x_t @ phix_w + b)  [65536, 1024]  (reads XbfT = GIP region start)
    gemm128<EPI_BF16_RELU><<<dim3(8, 512, 1), 256, 0, stream>>>(
        XbfT, nullptr, 512, 0, 512, phixWt, 512, phix_b, PHI, nullptr, 65536, 1024, 512, 512);
    // GIP = phi @ gru_wih[:H]  [65536, 3072]  (overwrites XbfT region)
    gemm128<EPI_BF16_NONE><<<dim3(24, 512, 1), 256, 0, stream>>>(
        PHI, nullptr, 1024, 0, 1024, wihPhiT, 1024, nullptr, GIP, nullptr, 65536, 3072, 1024, 1024);

    // ---- phase B: persistent sequential kernel ----
    init_ctr<<<1, 256, 0, stream>>>(bar);
    vrnn_seq<<<256, 256, 0, stream>>>(eps, em_b1, es_b1, em_b2, es_b2, gbih, gbhh,
                                      (char*)d_ws, out);

    // ---- phase C: deferred prior / decoder / loss ----
    gemm128<EPI_BF16_RELU><<<dim3(8, 512, 1), 256, 0, stream>>>(
        HS, nullptr, 1024, 0, 1024, pmW1T, 1024, pm_b1, PHI, nullptr, 65536, 1024, 1024, 1024);
    gemm128<EPI_F32_RELU><<<dim3(1, 512, 1), 256, 0, stream>>>(
        PHI, nullptr, 1024, 0, 1024, pmW2T, 1024, pm_b2, nullptr, PMbuf, 65536, 128, 1024, 1024);
    gemm128<EPI_BF16_RELU><<<dim3(8, 512, 1), 256, 0, stream>>>(
        HS, nullptr, 1024, 0, 1024, psW1T, 1024, ps_b1, PHI, nullptr, 65536, 1024, 1024, 1024);
    gemm128<EPI_F32_SP><<<dim3(1, 512, 1), 256, 0, stream>>>(
        PHI, nullptr, 1024, 0, 1024, psW2T, 1024, ps_b2, nullptr, PSbuf, 65536, 128, 1024, 1024);
    gemm128<EPI_BF16_RELU><<<dim3(8, 512, 1), 256, 0, stream>>>(
        HS, ZBF, 1024, 128, 1024, dmW1T, 1152, dm_b1, PHI, nullptr, 65536, 1024, 1152, 1152);
    gemm128<EPI_F32_SIG><<<dim3(4, 512, 1), 256, 0, stream>>>(
        PHI, nullptr, 1024, 0, 1024, dmW2T, 1024, dm_b2, nullptr, out + O_XM, 65536, 512, 1024, 1024);

    loss_per_t<<<256, 256, 0, stream>>>(x, out + O_XM, out + O_MU, out + O_STD,
                                        PMbuf, PSbuf, kldT, nllT);
    loss_final<<<1, 256, 0, stream>>>(kldT, nllT, out);
}